// Round 1
// baseline (2634.280 us; speedup 1.0000x reference)
//
#include <hip/hip_runtime.h>
#include <hip/hip_bf16.h>
#include <math.h>

// Problem constants
// B=4, L1=1024, D=512, H=16, DH=32, L=8192, R=8 (win=16, NW=512), DFF=2048

// ---------------------------------------------------------------------------
// 1) window stat: statT[b][n][c] = max-min over global_feat[b][c][n*16 .. +15]
// ---------------------------------------------------------------------------
__global__ __launch_bounds__(256) void window_stat_kernel(
    const float* __restrict__ gf, float* __restrict__ statT) {
  int g = blockIdx.x * 256 + threadIdx.x;       // 4*512*512 total
  int c = g & 511;
  int n = (g >> 9) & 511;
  int b = g >> 18;
  const float4* p = (const float4*)(gf + ((size_t)(b * 512 + c) << 13) + n * 16);
  float4 w0 = p[0], w1 = p[1], w2 = p[2], w3 = p[3];
  float mx = w0.x, mn = w0.x;
  mx = fmaxf(mx, w0.y); mn = fminf(mn, w0.y);
  mx = fmaxf(mx, w0.z); mn = fminf(mn, w0.z);
  mx = fmaxf(mx, w0.w); mn = fminf(mn, w0.w);
  mx = fmaxf(mx, w1.x); mn = fminf(mn, w1.x);
  mx = fmaxf(mx, w1.y); mn = fminf(mn, w1.y);
  mx = fmaxf(mx, w1.z); mn = fminf(mn, w1.z);
  mx = fmaxf(mx, w1.w); mn = fminf(mn, w1.w);
  mx = fmaxf(mx, w2.x); mn = fminf(mn, w2.x);
  mx = fmaxf(mx, w2.y); mn = fminf(mn, w2.y);
  mx = fmaxf(mx, w2.z); mn = fminf(mn, w2.z);
  mx = fmaxf(mx, w2.w); mn = fminf(mn, w2.w);
  mx = fmaxf(mx, w3.x); mn = fminf(mn, w3.x);
  mx = fmaxf(mx, w3.y); mn = fminf(mn, w3.y);
  mx = fmaxf(mx, w3.z); mn = fminf(mn, w3.z);
  mx = fmaxf(mx, w3.w); mn = fminf(mn, w3.w);
  statT[((size_t)(b * 512 + n) << 9) + c] = mx - mn;
}

// ---------------------------------------------------------------------------
// 2) generic f32 GEMM: C[m,n] = act(sum_k A[m,k]*W[n,k] + bias[n])
//    ACT: 0=none, 1=relu, 2=gelu(tanh approx, JAX default)
//    BM=BN=64, BK=16, 256 threads, 4x4 per thread. M%64==0, N%64==0, K%16==0.
// ---------------------------------------------------------------------------
template <int ACT>
__global__ __launch_bounds__(256) void gemm_xwT(
    const float* __restrict__ A, const float* __restrict__ W,
    const float* __restrict__ bias, float* __restrict__ C,
    int M, int N, int K) {
  __shared__ __align__(16) float As[16][68];  // [k][m], padded stride
  __shared__ __align__(16) float Bs[16][68];  // [k][n]
  const int t  = threadIdx.x;
  const int tx = t & 15, ty = t >> 4;
  const int m0 = blockIdx.y * 64, n0 = blockIdx.x * 64;
  const int lr = t >> 2;            // 0..63
  const int lc = (t & 3) * 4;       // 0,4,8,12
  const float* Ap = A + (size_t)(m0 + lr) * K + lc;
  const float* Wp = W + (size_t)(n0 + lr) * K + lc;
  float acc[4][4] = {{0.f}};
  for (int k0 = 0; k0 < K; k0 += 16) {
    float4 av = *(const float4*)(Ap + k0);
    float4 wv = *(const float4*)(Wp + k0);
    __syncthreads();  // previous iteration's reads complete
    As[lc + 0][lr] = av.x; As[lc + 1][lr] = av.y;
    As[lc + 2][lr] = av.z; As[lc + 3][lr] = av.w;
    Bs[lc + 0][lr] = wv.x; Bs[lc + 1][lr] = wv.y;
    Bs[lc + 2][lr] = wv.z; Bs[lc + 3][lr] = wv.w;
    __syncthreads();
#pragma unroll
    for (int kk = 0; kk < 16; ++kk) {
      float4 a4 = *(const float4*)&As[kk][ty * 4];
      float4 b4 = *(const float4*)&Bs[kk][tx * 4];
      float a[4] = {a4.x, a4.y, a4.z, a4.w};
      float b[4] = {b4.x, b4.y, b4.z, b4.w};
#pragma unroll
      for (int i = 0; i < 4; ++i)
#pragma unroll
        for (int j = 0; j < 4; ++j) acc[i][j] += a[i] * b[j];
    }
  }
#pragma unroll
  for (int i = 0; i < 4; ++i) {
    float4 o;
    float* oo = &o.x;
#pragma unroll
    for (int j = 0; j < 4; ++j) {
      float v = acc[i][j] + bias[n0 + tx * 4 + j];
      if (ACT == 1) v = fmaxf(v, 0.f);
      if (ACT == 2) {
        float xx = v;
        v = 0.5f * xx * (1.f + tanhf(0.7978845608028654f * (xx + 0.044715f * xx * xx * xx)));
      }
      oo[j] = v;
    }
    *(float4*)&C[(size_t)(m0 + ty * 4 + i) * N + n0 + tx * 4] = o;
  }
}

// ---------------------------------------------------------------------------
// 3) fused attention: per (qtile, head, batch). Q rows = b*1024+l (Lq=1024),
//    K/V rows = b*S+s. Head h = cols [h*32, h*32+32). 2-pass softmax in LDS.
// ---------------------------------------------------------------------------
template <int S, int QT>
__global__ __launch_bounds__(256) void attn_kernel(
    const float* __restrict__ Q, const float* __restrict__ K,
    const float* __restrict__ V, float* __restrict__ O) {
  constexpr int G   = 256 / QT;        // threads per query row
  constexpr int DPT = (QT * 32) / 256; // head dims per thread in PV
  const int qt = blockIdx.x, h = blockIdx.y, b = blockIdx.z;
  const int t  = threadIdx.x;
  const int qi = t / G, kg = t % G;
  __shared__ float qs[QT][32];
  __shared__ float sc[QT][S];
  __shared__ float red[QT][G];
  __shared__ float rowstat[QT];
  const int l0 = qt * QT;
  for (int i = t; i < QT * 32; i += 256) {
    int r = i >> 5, e = i & 31;
    qs[r][e] = Q[(size_t)(b * 1024 + l0 + r) * 512 + h * 32 + e];
  }
  __syncthreads();
  const float scale = 0.17677669529663687f;  // 1/sqrt(32)
  for (int s = kg; s < S; s += G) {
    const float* kp = K + (size_t)(b * S + s) * 512 + h * 32;
    float acc = 0.f;
#pragma unroll
    for (int e = 0; e < 32; ++e) acc += qs[qi][e] * kp[e];
    sc[qi][s] = acc * scale;
  }
  __syncthreads();
  float m = -1e30f;
  for (int s = kg; s < S; s += G) m = fmaxf(m, sc[qi][s]);
  red[qi][kg] = m;
  __syncthreads();
  if (kg == 0) {
    float mm = red[qi][0];
    for (int i = 1; i < G; ++i) mm = fmaxf(mm, red[qi][i]);
    rowstat[qi] = mm;
  }
  __syncthreads();
  const float mrow = rowstat[qi];
  float ps = 0.f;
  for (int s = kg; s < S; s += G) {
    float e = __expf(sc[qi][s] - mrow);
    sc[qi][s] = e;
    ps += e;
  }
  red[qi][kg] = ps;
  __syncthreads();
  if (kg == 0) {
    float ss = 0.f;
    for (int i = 0; i < G; ++i) ss += red[qi][i];
    rowstat[qi] = ss;
  }
  __syncthreads();
  const float inv = 1.f / rowstat[qi];
  float acc[DPT];
#pragma unroll
  for (int d = 0; d < DPT; ++d) acc[d] = 0.f;
  const int d0 = kg * DPT;
  for (int s = 0; s < S; ++s) {
    const float p = sc[qi][s];
    const float* vp = V + (size_t)(b * S + s) * 512 + h * 32 + d0;
#pragma unroll
    for (int d = 0; d < DPT; ++d) acc[d] += p * vp[d];
  }
  float* op = O + (size_t)(b * 1024 + l0 + qi) * 512 + h * 32 + d0;
#pragma unroll
  for (int d = 0; d < DPT; ++d) op[d] = acc[d] * inv;
}

// ---------------------------------------------------------------------------
// 4) LayerNorm(X + A) * g + b ; row length 512; optional transposed store
//    transpose: row r = b*1024+l  ->  O[b*512*1024 + c*1024 + l]
// ---------------------------------------------------------------------------
__global__ __launch_bounds__(256) void ln_res_kernel(
    const float* __restrict__ X, const float* __restrict__ A,
    const float* __restrict__ g, const float* __restrict__ be,
    float* __restrict__ O, int transpose_out) {
  const int r = blockIdx.x;
  const int t = threadIdx.x;
  const size_t base = (size_t)r * 512;
  float v0 = X[base + t] + A[base + t];
  float v1 = X[base + t + 256] + A[base + t + 256];
  __shared__ float wsum[4];
  float s = v0 + v1;
#pragma unroll
  for (int o = 32; o; o >>= 1) s += __shfl_down(s, o);
  if ((t & 63) == 0) wsum[t >> 6] = s;
  __syncthreads();
  const float mean = (wsum[0] + wsum[1] + wsum[2] + wsum[3]) * (1.f / 512.f);
  __syncthreads();
  float d0 = v0 - mean, d1 = v1 - mean;
  float s2 = d0 * d0 + d1 * d1;
#pragma unroll
  for (int o = 32; o; o >>= 1) s2 += __shfl_down(s2, o);
  if ((t & 63) == 0) wsum[t >> 6] = s2;
  __syncthreads();
  const float var  = (wsum[0] + wsum[1] + wsum[2] + wsum[3]) * (1.f / 512.f);
  const float rstd = rsqrtf(var + 1e-5f);
  float o0 = d0 * rstd * g[t] + be[t];
  float o1 = d1 * rstd * g[t + 256] + be[t + 256];
  if (!transpose_out) {
    O[base + t] = o0;
    O[base + t + 256] = o1;
  } else {
    int b = r >> 10, l = r & 1023;
    O[((size_t)(b * 512) + t) * 1024 + l] = o0;
    O[((size_t)(b * 512) + t + 256) * 1024 + l] = o1;
  }
}

// ---------------------------------------------------------------------------
extern "C" void kernel_launch(void* const* d_in, const int* in_sizes, int n_in,
                              void* d_out, int out_size, void* d_ws, size_t ws_size,
                              hipStream_t stream) {
  const float* x      = (const float*)d_in[0];
  const float* gf     = (const float*)d_in[1];
  const float* conv_w = (const float*)d_in[2];
  const float* conv_b = (const float*)d_in[3];
  const float* sWq = (const float*)d_in[4],  *sbq = (const float*)d_in[5];
  const float* sWk = (const float*)d_in[6],  *sbk = (const float*)d_in[7];
  const float* sWv = (const float*)d_in[8],  *sbv = (const float*)d_in[9];
  const float* sWo = (const float*)d_in[10], *sbo = (const float*)d_in[11];
  const float* cWq = (const float*)d_in[12], *cbq = (const float*)d_in[13];
  const float* cWk = (const float*)d_in[14], *cbk = (const float*)d_in[15];
  const float* cWv = (const float*)d_in[16], *cbv = (const float*)d_in[17];
  const float* cWo = (const float*)d_in[18], *cbo = (const float*)d_in[19];
  const float* fw1 = (const float*)d_in[20], *fb1 = (const float*)d_in[21];
  const float* fw2 = (const float*)d_in[22], *fb2 = (const float*)d_in[23];
  const float* ln1_g = (const float*)d_in[24], *ln1_b = (const float*)d_in[25];
  const float* ln2_g = (const float*)d_in[26], *ln2_b = (const float*)d_in[27];
  const float* ln3_g = (const float*)d_in[28], *ln3_b = (const float*)d_in[29];
  float* out = (float*)d_out;
  float* ws  = (float*)d_ws;

  const size_t M1 = 1048576;  // 1M floats
  float* statT = ws;            // [4,512,512]   0..1M
  float* cross = ws + M1;       // [4,512,512]   1M..2M
  float* q     = ws + 2 * M1;   // [4096,512]    2M..4M
  float* k     = ws + 4 * M1;   // 4M..6M  (k2 uses first 1M)
  float* v     = ws + 6 * M1;   // 6M..8M
  float* ctx   = ws + 8 * M1;   // 8M..10M
  float* proj  = ws + 10 * M1;  // 10M..12M
  float* h     = ws + 12 * M1;  // 12M..14M
  float* h2    = ws;            // 2M, reuses statT+cross (free by then)
  float* mid   = ws + 2 * M1;   // [4096,2048] 8M floats, reuses q/k/v/ctx
  float* y     = ws + 10 * M1;  // reuses proj

  // 1) window stats (transposed) ; 2) pointwise conv + relu -> cross tokens
  window_stat_kernel<<<4096, 256, 0, stream>>>(gf, statT);
  gemm_xwT<1><<<dim3(8, 32), 256, 0, stream>>>(statT, conv_w, conv_b, cross, 2048, 512, 512);

  // 3) self-attention
  gemm_xwT<0><<<dim3(8, 64), 256, 0, stream>>>(x, sWq, sbq, q, 4096, 512, 512);
  gemm_xwT<0><<<dim3(8, 64), 256, 0, stream>>>(x, sWk, sbk, k, 4096, 512, 512);
  gemm_xwT<0><<<dim3(8, 64), 256, 0, stream>>>(x, sWv, sbv, v, 4096, 512, 512);
  attn_kernel<1024, 8><<<dim3(128, 16, 4), 256, 0, stream>>>(q, k, v, ctx);
  gemm_xwT<0><<<dim3(8, 64), 256, 0, stream>>>(ctx, sWo, sbo, proj, 4096, 512, 512);
  ln_res_kernel<<<4096, 256, 0, stream>>>(x, proj, ln1_g, ln1_b, h, 0);

  // 4) cross-attention (K/V from conv tokens, S=512)
  gemm_xwT<0><<<dim3(8, 64), 256, 0, stream>>>(h, cWq, cbq, q, 4096, 512, 512);
  gemm_xwT<0><<<dim3(8, 32), 256, 0, stream>>>(cross, cWk, cbk, k, 2048, 512, 512);
  gemm_xwT<0><<<dim3(8, 32), 256, 0, stream>>>(cross, cWv, cbv, v, 2048, 512, 512);
  attn_kernel<512, 16><<<dim3(64, 16, 4), 256, 0, stream>>>(q, k, v, ctx);
  gemm_xwT<0><<<dim3(8, 64), 256, 0, stream>>>(ctx, cWo, cbo, proj, 4096, 512, 512);
  ln_res_kernel<<<4096, 256, 0, stream>>>(h, proj, ln2_g, ln2_b, h2, 0);

  // 5) FFN + final LN (transposed store)
  gemm_xwT<2><<<dim3(32, 64), 256, 0, stream>>>(h2, fw1, fb1, mid, 4096, 2048, 512);
  gemm_xwT<0><<<dim3(8, 64), 256, 0, stream>>>(mid, fw2, fb2, y, 4096, 512, 2048);
  ln_res_kernel<<<4096, 256, 0, stream>>>(h2, y, ln3_g, ln3_b, out, 1);
}

// Round 3
// 475.694 us; speedup vs baseline: 5.5378x; 5.5378x over previous
//
#include <hip/hip_runtime.h>
#include <stdint.h>
#include <math.h>

// B=4, L1=1024, D=512, H=16, DH=32, L=8192, win=16, NW=512, DFF=2048

typedef short  s16x8 __attribute__((ext_vector_type(8)));
typedef float  f32x4 __attribute__((ext_vector_type(4)));

__device__ inline unsigned short f2bf(float f) {
  uint32_t u = __builtin_bit_cast(uint32_t, f);
  u += 0x7fffu + ((u >> 16) & 1u);
  return (unsigned short)(u >> 16);
}
__device__ inline float bf2f(unsigned short h) {
  uint32_t u = ((uint32_t)h) << 16;
  return __builtin_bit_cast(float, u);
}

// ---------------------------------------------------------------------------
// 0) fused f32 -> bf16 conversion of x + all weights into one contiguous pool
// ---------------------------------------------------------------------------
__global__ __launch_bounds__(256) void convert_bf16_kernel(
    const float* s0, const float* s1, const float* s2, const float* s3,
    const float* s4, const float* s5, const float* s6, const float* s7,
    const float* s8, const float* s9, const float* s10, const float* s11,
    unsigned short* dst) {
  const size_t cum[13] = {0, 262144, 524288, 786432, 1048576, 1310720,
                          1572864, 1835008, 2097152, 2359296, 3407872,
                          4456448, 6553600};
  const float* srcs[12] = {s0, s1, s2, s3, s4, s5, s6, s7, s8, s9, s10, s11};
  size_t e0 = ((size_t)blockIdx.x * 256 + threadIdx.x) * 8;
  int seg = 0;
  while (e0 >= cum[seg + 1]) ++seg;
  const float* sp = srcs[seg] + (e0 - cum[seg]);
  float4 a = *(const float4*)sp;
  float4 b = *(const float4*)(sp + 4);
  unsigned short o[8] = {f2bf(a.x), f2bf(a.y), f2bf(a.z), f2bf(a.w),
                         f2bf(b.x), f2bf(b.y), f2bf(b.z), f2bf(b.w)};
  *(uint4*)&dst[e0] = *(const uint4*)o;
}

// ---------------------------------------------------------------------------
// 1) window stat -> bf16, transposed: statT[b][n][c] = |max-min| over window
// ---------------------------------------------------------------------------
__global__ __launch_bounds__(256) void window_stat_kernel(
    const float* __restrict__ gf, unsigned short* __restrict__ statT) {
  int gidx = blockIdx.x * 256 + threadIdx.x;
  int c = gidx & 511;
  int n = (gidx >> 9) & 511;
  int b = gidx >> 18;
  const float4* p = (const float4*)(gf + ((size_t)(b * 512 + c) << 13) + n * 16);
  float4 w0 = p[0], w1 = p[1], w2 = p[2], w3 = p[3];
  float mx = w0.x, mn = w0.x;
  float vals[15] = {w0.y, w0.z, w0.w, w1.x, w1.y, w1.z, w1.w,
                    w2.x, w2.y, w2.z, w2.w, w3.x, w3.y, w3.z, w3.w};
#pragma unroll
  for (int i = 0; i < 15; ++i) {
    mx = fmaxf(mx, vals[i]);
    mn = fminf(mn, vals[i]);
  }
  statT[((size_t)(b * 512 + n) << 9) + c] = f2bf(mx - mn);
}

// ---------------------------------------------------------------------------
// 2) bf16 MFMA GEMM (m97 structure): C[m,n] = act(sum_k A[m,k]*W[n,k]+bias[n])
//    BM=BN=128, BK=32, 4 waves (2x2), 4x4 16x16x32 frags per wave.
//    ACT: 0 none, 1 relu, 2 gelu-tanh. OUTBF: 1 -> bf16 out, 0 -> f32 out.
// ---------------------------------------------------------------------------
template <int ACT, int OUTBF>
__global__ __launch_bounds__(256) void gemm_bf16(
    const unsigned short* __restrict__ A, const unsigned short* __restrict__ W,
    const float* __restrict__ bias, void* __restrict__ Cout,
    int M, int N, int K) {
  __shared__ unsigned short As[128 * 32];
  __shared__ unsigned short Bs[128 * 32];
  const int t = threadIdx.x;
  const int w = t >> 6, lane = t & 63;
  const int r = lane & 15, g = lane >> 4;
  const int wm = w >> 1, wn = w & 1;
  const int m0 = blockIdx.y * 128, n0 = blockIdx.x * 128;

  f32x4 acc[4][4];
#pragma unroll
  for (int mi = 0; mi < 4; ++mi)
#pragma unroll
    for (int ni = 0; ni < 4; ++ni) acc[mi][ni] = (f32x4){0.f, 0.f, 0.f, 0.f};

  for (int k0 = 0; k0 < K; k0 += 32) {
#pragma unroll
    for (int ii = 0; ii < 2; ++ii) {
      int c = t + 256 * ii;
      int row = c >> 2, seg = c & 3;
      const unsigned short* ga = A + (size_t)(m0 + row) * K + k0 + seg * 8;
      __builtin_amdgcn_global_load_lds(
          (const __attribute__((address_space(1))) uint32_t*)ga,
          (__attribute__((address_space(3))) uint32_t*)&As[c * 8], 16, 0, 0);
      const unsigned short* gb = W + (size_t)(n0 + row) * K + k0 + seg * 8;
      __builtin_amdgcn_global_load_lds(
          (const __attribute__((address_space(1))) uint32_t*)gb,
          (__attribute__((address_space(3))) uint32_t*)&Bs[c * 8], 16, 0, 0);
    }
    __syncthreads();
    s16x8 af[4], bf[4];
#pragma unroll
    for (int mi = 0; mi < 4; ++mi)
      af[mi] = *(const s16x8*)&As[(wm * 64 + mi * 16 + r) * 32 + g * 8];
#pragma unroll
    for (int ni = 0; ni < 4; ++ni)
      bf[ni] = *(const s16x8*)&Bs[(wn * 64 + ni * 16 + r) * 32 + g * 8];
#pragma unroll
    for (int mi = 0; mi < 4; ++mi)
#pragma unroll
      for (int ni = 0; ni < 4; ++ni)
        acc[mi][ni] = __builtin_amdgcn_mfma_f32_16x16x32_bf16(
            af[mi], bf[ni], acc[mi][ni], 0, 0, 0);
    __syncthreads();
  }

#pragma unroll
  for (int ni = 0; ni < 4; ++ni) {
    const int col = n0 + wn * 64 + ni * 16 + r;
    const float bv = bias[col];
#pragma unroll
    for (int mi = 0; mi < 4; ++mi) {
#pragma unroll
      for (int rg = 0; rg < 4; ++rg) {
        const int row = m0 + wm * 64 + mi * 16 + g * 4 + rg;
        float v = acc[mi][ni][rg] + bv;
        if (ACT == 1) v = fmaxf(v, 0.f);
        if (ACT == 2) {
          float u = 0.7978845608028654f * (v + 0.044715f * v * v * v);
          float e = __expf(2.f * u);
          float th = 1.f - 2.f / (e + 1.f);
          v = 0.5f * v * (1.f + th);
        }
        if (OUTBF)
          ((unsigned short*)Cout)[(size_t)row * N + col] = f2bf(v);
        else
          ((float*)Cout)[(size_t)row * N + col] = v;
      }
    }
  }
}

// ---------------------------------------------------------------------------
// 3) V transpose per (b,h): V[b*S+s][h*32+d] -> VT[(b*16+h)*32+d][s]
// ---------------------------------------------------------------------------
template <int S>
__global__ __launch_bounds__(256) void vtrans_kernel(
    const unsigned short* __restrict__ V, unsigned short* __restrict__ VT) {
  const int b = blockIdx.z, h = blockIdx.y, s0 = blockIdx.x * 64;
  const int t = threadIdx.x;
  __shared__ unsigned short tile[64 * 40];
  {
    int i = t >> 2, seg = t & 3;
    *(uint4*)&tile[i * 40 + seg * 8] =
        *(const uint4*)&V[((size_t)(b * S + s0 + i)) * 512 + h * 32 + seg * 8];
  }
  __syncthreads();
  {
    int d = t >> 3, j = t & 7;
    unsigned short vals[8];
#pragma unroll
    for (int u = 0; u < 8; ++u) vals[u] = tile[(j * 8 + u) * 40 + d];
    *(uint4*)&VT[((size_t)((b * 16 + h) * 32 + d)) * S + s0 + j * 8] =
        *(const uint4*)vals;
  }
}

// ---------------------------------------------------------------------------
// 4) MFMA flash attention. Block = (qtile of 128 rows, head, batch), 4 waves.
//    Each wave: 32 q rows. K staged [128][40] LDS, VT staged [32][136],
//    P routed via per-wave LDS [32][136]. Online softmax, f32 state.
// ---------------------------------------------------------------------------
template <int S>
__global__ __launch_bounds__(256) void attn_mfma(
    const unsigned short* __restrict__ Q, const unsigned short* __restrict__ K,
    const unsigned short* __restrict__ VT, unsigned short* __restrict__ O) {
  constexpr int NT = S / 128;
  __shared__ unsigned short Kl[128 * 40];
  __shared__ unsigned short Vl[32 * 136];
  __shared__ unsigned short Pl[4][32 * 136];
  const int t = threadIdx.x;
  const int w = t >> 6, lane = t & 63;
  const int r = lane & 15, g = lane >> 4;
  const int qt = blockIdx.x, h = blockIdx.y, b = blockIdx.z;
  const int q0 = qt * 128 + w * 32;
  const float scale = 0.17677669529663687f;  // 1/sqrt(32)

  s16x8 qa[2];
#pragma unroll
  for (int i = 0; i < 2; ++i)
    qa[i] = *(const s16x8*)&Q[((size_t)(b * 1024 + q0 + i * 16 + r)) * 512 +
                              h * 32 + g * 8];

  f32x4 o[2][2];
  float mr[2][4], lr[2][4];
#pragma unroll
  for (int i = 0; i < 2; ++i) {
#pragma unroll
    for (int nd = 0; nd < 2; ++nd) o[i][nd] = (f32x4){0.f, 0.f, 0.f, 0.f};
#pragma unroll
    for (int rg = 0; rg < 4; ++rg) { mr[i][rg] = -1e30f; lr[i][rg] = 0.f; }
  }

  for (int nt = 0; nt < NT; ++nt) {
    const int kv0 = nt * 128;
    // stage K tile: 512 x 16B chunks
#pragma unroll
    for (int ii = 0; ii < 2; ++ii) {
      int c = t + 256 * ii;
      int row = c >> 2, seg = c & 3;
      *(uint4*)&Kl[row * 40 + seg * 8] =
          *(const uint4*)&K[((size_t)(b * S + kv0 + row)) * 512 + h * 32 + seg * 8];
    }
    // stage VT tile: 512 x 16B chunks
#pragma unroll
    for (int ii = 0; ii < 2; ++ii) {
      int c = t + 256 * ii;
      int d = c >> 4, sc = c & 15;
      *(uint4*)&Vl[d * 136 + sc * 8] =
          *(const uint4*)&VT[((size_t)((b * 16 + h) * 32 + d)) * S + kv0 + sc * 8];
    }
    __syncthreads();

    // QK^T: s[i][nb] covers q rows (i*16..) x kv cols (nb*16..)
    f32x4 s[2][8];
#pragma unroll
    for (int nb = 0; nb < 8; ++nb) {
      s16x8 kb = *(const s16x8*)&Kl[(nb * 16 + r) * 40 + g * 8];
      s[0][nb] = __builtin_amdgcn_mfma_f32_16x16x32_bf16(
          qa[0], kb, (f32x4){0.f, 0.f, 0.f, 0.f}, 0, 0, 0);
      s[1][nb] = __builtin_amdgcn_mfma_f32_16x16x32_bf16(
          qa[1], kb, (f32x4){0.f, 0.f, 0.f, 0.f}, 0, 0, 0);
    }

    // online softmax; lane's rows: q = i*16 + g*4 + rg, col = nb*16 + r
#pragma unroll
    for (int i = 0; i < 2; ++i) {
#pragma unroll
      for (int rg = 0; rg < 4; ++rg) {
        float tm = s[i][0][rg];
#pragma unroll
        for (int nb = 1; nb < 8; ++nb) tm = fmaxf(tm, s[i][nb][rg]);
        tm = fmaxf(tm, __shfl_xor(tm, 1));
        tm = fmaxf(tm, __shfl_xor(tm, 2));
        tm = fmaxf(tm, __shfl_xor(tm, 4));
        tm = fmaxf(tm, __shfl_xor(tm, 8));
        tm *= scale;
        const float mold = mr[i][rg];
        const float mnew = fmaxf(mold, tm);
        const float corr = __expf(mold - mnew);
        float ps = 0.f;
#pragma unroll
        for (int nb = 0; nb < 8; ++nb) {
          float p = __expf(s[i][nb][rg] * scale - mnew);
          ps += p;
          Pl[w][(i * 16 + g * 4 + rg) * 136 + nb * 16 + r] = f2bf(p);
        }
        ps += __shfl_xor(ps, 1);
        ps += __shfl_xor(ps, 2);
        ps += __shfl_xor(ps, 4);
        ps += __shfl_xor(ps, 8);
        lr[i][rg] = lr[i][rg] * corr + ps;
        mr[i][rg] = mnew;
        o[i][0][rg] *= corr;
        o[i][1][rg] *= corr;
      }
    }

    // PV: O[q][d] += P[q][s] * V[s][d]
#pragma unroll
    for (int ks = 0; ks < 4; ++ks) {
      s16x8 pa0 = *(const s16x8*)&Pl[w][(r) * 136 + ks * 32 + g * 8];
      s16x8 pa1 = *(const s16x8*)&Pl[w][(16 + r) * 136 + ks * 32 + g * 8];
      s16x8 vb0 = *(const s16x8*)&Vl[(r) * 136 + ks * 32 + g * 8];
      s16x8 vb1 = *(const s16x8*)&Vl[(16 + r) * 136 + ks * 32 + g * 8];
      o[0][0] = __builtin_amdgcn_mfma_f32_16x16x32_bf16(pa0, vb0, o[0][0], 0, 0, 0);
      o[0][1] = __builtin_amdgcn_mfma_f32_16x16x32_bf16(pa0, vb1, o[0][1], 0, 0, 0);
      o[1][0] = __builtin_amdgcn_mfma_f32_16x16x32_bf16(pa1, vb0, o[1][0], 0, 0, 0);
      o[1][1] = __builtin_amdgcn_mfma_f32_16x16x32_bf16(pa1, vb1, o[1][1], 0, 0, 0);
    }
    __syncthreads();
  }

#pragma unroll
  for (int i = 0; i < 2; ++i) {
#pragma unroll
    for (int rg = 0; rg < 4; ++rg) {
      const float inv = 1.f / lr[i][rg];
      const size_t row = (size_t)(b * 1024 + qt * 128 + w * 32 + i * 16 + g * 4 + rg);
#pragma unroll
      for (int nd = 0; nd < 2; ++nd)
        O[row * 512 + h * 32 + nd * 16 + r] = f2bf(o[i][nd][rg] * inv);
    }
  }
}

// ---------------------------------------------------------------------------
// 5) LayerNorm(X + A) * g + b.  XBF: X is bf16. MODE 0: bf16 out [row][512];
//    MODE 1: f32 out transposed to [b][c][l].
// ---------------------------------------------------------------------------
template <int XBF, int MODE>
__global__ __launch_bounds__(256) void ln_kernel(
    const void* __restrict__ X, const float* __restrict__ A,
    const float* __restrict__ gw, const float* __restrict__ bw,
    void* __restrict__ O) {
  const int rr = blockIdx.x;
  const int t = threadIdx.x;
  const size_t base = (size_t)rr * 512;
  float x0, x1;
  if (XBF) {
    x0 = bf2f(((const unsigned short*)X)[base + t]);
    x1 = bf2f(((const unsigned short*)X)[base + t + 256]);
  } else {
    x0 = ((const float*)X)[base + t];
    x1 = ((const float*)X)[base + t + 256];
  }
  float v0 = x0 + A[base + t];
  float v1 = x1 + A[base + t + 256];
  __shared__ float wsum[4];
  float s = v0 + v1;
#pragma unroll
  for (int of = 32; of; of >>= 1) s += __shfl_down(s, of);
  if ((t & 63) == 0) wsum[t >> 6] = s;
  __syncthreads();
  const float mean = (wsum[0] + wsum[1] + wsum[2] + wsum[3]) * (1.f / 512.f);
  __syncthreads();
  float d0 = v0 - mean, d1 = v1 - mean;
  float s2 = d0 * d0 + d1 * d1;
#pragma unroll
  for (int of = 32; of; of >>= 1) s2 += __shfl_down(s2, of);
  if ((t & 63) == 0) wsum[t >> 6] = s2;
  __syncthreads();
  const float var = (wsum[0] + wsum[1] + wsum[2] + wsum[3]) * (1.f / 512.f);
  const float rstd = rsqrtf(var + 1e-5f);
  float o0 = d0 * rstd * gw[t] + bw[t];
  float o1 = d1 * rstd * gw[t + 256] + bw[t + 256];
  if (MODE == 0) {
    ((unsigned short*)O)[base + t] = f2bf(o0);
    ((unsigned short*)O)[base + t + 256] = f2bf(o1);
  } else {
    int b = rr >> 10, l = rr & 1023;
    ((float*)O)[((size_t)(b * 512) + t) * 1024 + l] = o0;
    ((float*)O)[((size_t)(b * 512) + t + 256) * 1024 + l] = o1;
  }
}

// ---------------------------------------------------------------------------
extern "C" void kernel_launch(void* const* d_in, const int* in_sizes, int n_in,
                              void* d_out, int out_size, void* d_ws, size_t ws_size,
                              hipStream_t stream) {
  const float* x      = (const float*)d_in[0];
  const float* gf     = (const float*)d_in[1];
  const float* conv_w = (const float*)d_in[2];
  const float* conv_b = (const float*)d_in[3];
  const float* sWq = (const float*)d_in[4],  *sbq = (const float*)d_in[5];
  const float* sWk = (const float*)d_in[6],  *sbk = (const float*)d_in[7];
  const float* sWv = (const float*)d_in[8],  *sbv = (const float*)d_in[9];
  const float* sWo = (const float*)d_in[10], *sbo = (const float*)d_in[11];
  const float* cWq = (const float*)d_in[12], *cbq = (const float*)d_in[13];
  const float* cWk = (const float*)d_in[14], *cbk = (const float*)d_in[15];
  const float* cWv = (const float*)d_in[16], *cbv = (const float*)d_in[17];
  const float* cWo = (const float*)d_in[18], *cbo = (const float*)d_in[19];
  const float* fw1 = (const float*)d_in[20], *fb1 = (const float*)d_in[21];
  const float* fw2 = (const float*)d_in[22], *fb2 = (const float*)d_in[23];
  const float* ln1_g = (const float*)d_in[24], *ln1_b = (const float*)d_in[25];
  const float* ln2_g = (const float*)d_in[26], *ln2_b = (const float*)d_in[27];
  const float* ln3_g = (const float*)d_in[28], *ln3_b = (const float*)d_in[29];
  float* out = (float*)d_out;
  float* ws  = (float*)d_ws;

  // bf16 conversion pool (element offsets into ushort view of ws):
  unsigned short* bfp = (unsigned short*)ws;
  unsigned short* conv_wb = bfp + 0;
  unsigned short* sWqb = bfp + 262144,  *sWkb = bfp + 524288;
  unsigned short* sWvb = bfp + 786432,  *sWob = bfp + 1048576;
  unsigned short* cWqb = bfp + 1310720, *cWkb = bfp + 1572864;
  unsigned short* cWvb = bfp + 1835008, *cWob = bfp + 2097152;
  unsigned short* fw1b = bfp + 2359296, *fw2b = bfp + 3407872;
  unsigned short* xbf  = bfp + 4456448;   // pool ends at el 6553600 (fl 3276800)
  float* proj = ws + 3276800;             // 2M floats, also reused as y
  unsigned short* SC = (unsigned short*)(ws + 5373952);
  unsigned short* statTb = SC + 0;
  unsigned short* crossb = SC + 1048576;
  unsigned short* qb   = SC + 2097152;
  unsigned short* kb   = SC + 4194304;
  unsigned short* vb   = SC + 6291456;
  unsigned short* vtb  = SC + 8388608;
  unsigned short* ctxb = SC + 10485760;
  unsigned short* hbf  = SC + 12582912;
  unsigned short* h2bf = SC + 14680064;
  unsigned short* midb = qb;              // 8M el, overlays qb..vtb (dead then)

  convert_bf16_kernel<<<3200, 256, 0, stream>>>(
      conv_w, sWq, sWk, sWv, sWo, cWq, cWk, cWv, cWo, fw1, fw2, x, bfp);

  window_stat_kernel<<<4096, 256, 0, stream>>>(gf, statTb);
  gemm_bf16<1, 1><<<dim3(4, 16), 256, 0, stream>>>(statTb, conv_wb, conv_b, crossb, 2048, 512, 512);

  // self-attention
  gemm_bf16<0, 1><<<dim3(4, 32), 256, 0, stream>>>(xbf, sWqb, sbq, qb, 4096, 512, 512);
  gemm_bf16<0, 1><<<dim3(4, 32), 256, 0, stream>>>(xbf, sWkb, sbk, kb, 4096, 512, 512);
  gemm_bf16<0, 1><<<dim3(4, 32), 256, 0, stream>>>(xbf, sWvb, sbv, vb, 4096, 512, 512);
  vtrans_kernel<1024><<<dim3(16, 16, 4), 256, 0, stream>>>(vb, vtb);
  attn_mfma<1024><<<dim3(8, 16, 4), 256, 0, stream>>>(qb, kb, vtb, ctxb);
  gemm_bf16<0, 0><<<dim3(4, 32), 256, 0, stream>>>(ctxb, sWob, sbo, proj, 4096, 512, 512);
  ln_kernel<0, 0><<<4096, 256, 0, stream>>>(x, proj, ln1_g, ln1_b, hbf);

  // cross-attention (K/V from conv tokens, S=512)
  gemm_bf16<0, 1><<<dim3(4, 32), 256, 0, stream>>>(hbf, cWqb, cbq, qb, 4096, 512, 512);
  gemm_bf16<0, 1><<<dim3(4, 16), 256, 0, stream>>>(crossb, cWkb, cbk, kb, 2048, 512, 512);
  gemm_bf16<0, 1><<<dim3(4, 16), 256, 0, stream>>>(crossb, cWvb, cbv, vb, 2048, 512, 512);
  vtrans_kernel<512><<<dim3(8, 16, 4), 256, 0, stream>>>(vb, vtb);
  attn_mfma<512><<<dim3(8, 16, 4), 256, 0, stream>>>(qb, kb, vtb, ctxb);
  gemm_bf16<0, 0><<<dim3(4, 32), 256, 0, stream>>>(ctxb, cWob, cbo, proj, 4096, 512, 512);
  ln_kernel<1, 0><<<4096, 256, 0, stream>>>(hbf, proj, ln2_g, ln2_b, h2bf);

  // FFN + final LN (transposed f32 out)
  gemm_bf16<2, 1><<<dim3(16, 32), 256, 0, stream>>>(h2bf, fw1b, fb1, midb, 4096, 2048, 512);
  gemm_bf16<0, 0><<<dim3(4, 32), 256, 0, stream>>>(midb, fw2b, fb2, proj, 4096, 512, 2048);
  ln_kernel<1, 1><<<4096, 256, 0, stream>>>(h2bf, proj, ln3_g, ln3_b, out);
}

// Round 4
// 418.531 us; speedup vs baseline: 6.2941x; 1.1366x over previous
//
#include <hip/hip_runtime.h>
#include <stdint.h>
#include <math.h>

// B=4, L1=1024, D=512, H=16, DH=32, L=8192, win=16, NW=512, DFF=2048

typedef short  s16x8 __attribute__((ext_vector_type(8)));
typedef float  f32x4 __attribute__((ext_vector_type(4)));

__device__ inline unsigned short f2bf(float f) {
  uint32_t u = __builtin_bit_cast(uint32_t, f);
  u += 0x7fffu + ((u >> 16) & 1u);
  return (unsigned short)(u >> 16);
}
__device__ inline float bf2f(unsigned short h) {
  uint32_t u = ((uint32_t)h) << 16;
  return __builtin_bit_cast(float, u);
}

// scale(1/sqrt(32)) * log2(e): folded into Q so softmax is pure exp2
#define QSCALE 0.25503486611627154f

// ---------------------------------------------------------------------------
// 0) fused f32 -> bf16 conversion of x + all weights into one contiguous pool
// ---------------------------------------------------------------------------
__global__ __launch_bounds__(256) void convert_bf16_kernel(
    const float* s0, const float* s1, const float* s2, const float* s3,
    const float* s4, const float* s5, const float* s6, const float* s7,
    const float* s8, const float* s9, const float* s10, const float* s11,
    unsigned short* dst) {
  const size_t cum[13] = {0, 262144, 524288, 786432, 1048576, 1310720,
                          1572864, 1835008, 2097152, 2359296, 3407872,
                          4456448, 6553600};
  const float* srcs[12] = {s0, s1, s2, s3, s4, s5, s6, s7, s8, s9, s10, s11};
  size_t e0 = ((size_t)blockIdx.x * 256 + threadIdx.x) * 8;
  int seg = 0;
  while (e0 >= cum[seg + 1]) ++seg;
  const float* sp = srcs[seg] + (e0 - cum[seg]);
  float4 a = *(const float4*)sp;
  float4 b = *(const float4*)(sp + 4);
  unsigned short o[8] = {f2bf(a.x), f2bf(a.y), f2bf(a.z), f2bf(a.w),
                         f2bf(b.x), f2bf(b.y), f2bf(b.z), f2bf(b.w)};
  *(uint4*)&dst[e0] = *(const uint4*)o;
}

// ---------------------------------------------------------------------------
// 1) window stat -> bf16, transposed: statT[b][n][c] = |max-min| over window
// ---------------------------------------------------------------------------
__global__ __launch_bounds__(256) void window_stat_kernel(
    const float* __restrict__ gf, unsigned short* __restrict__ statT) {
  int gidx = blockIdx.x * 256 + threadIdx.x;
  int c = gidx & 511;
  int n = (gidx >> 9) & 511;
  int b = gidx >> 18;
  const float4* p = (const float4*)(gf + ((size_t)(b * 512 + c) << 13) + n * 16);
  float4 w0 = p[0], w1 = p[1], w2 = p[2], w3 = p[3];
  float mx = w0.x, mn = w0.x;
  float vals[15] = {w0.y, w0.z, w0.w, w1.x, w1.y, w1.z, w1.w,
                    w2.x, w2.y, w2.z, w2.w, w3.x, w3.y, w3.z, w3.w};
#pragma unroll
  for (int i = 0; i < 15; ++i) {
    mx = fmaxf(mx, vals[i]);
    mn = fminf(mn, vals[i]);
  }
  statT[((size_t)(b * 512 + n) << 9) + c] = f2bf(mx - mn);
}

// ---------------------------------------------------------------------------
// 1b) concat QKV / cross-KV biases into one f32 buffer [1536 | 1024]
// ---------------------------------------------------------------------------
__global__ __launch_bounds__(256) void biascat_kernel(
    const float* __restrict__ sbq, const float* __restrict__ sbk,
    const float* __restrict__ sbv, const float* __restrict__ cbk,
    const float* __restrict__ cbv, float* __restrict__ dst) {
  int i = blockIdx.x * 256 + threadIdx.x;  // 2560 total
  float v;
  if (i < 512) v = sbq[i];
  else if (i < 1024) v = sbk[i - 512];
  else if (i < 1536) v = sbv[i - 1024];
  else if (i < 2048) v = cbk[i - 1536];
  else v = cbv[i - 2048];
  dst[i] = v;
}

// ---------------------------------------------------------------------------
// 2) bf16 MFMA GEMM: C[m,n] = act(sum_k A[m,k]*W[n,k] + bias[n])
//    BM=64, BN=128, BK=32, 4 waves (2x2), per-wave 32x64 (2x4 16x16x32 frags).
//    ACT: 0 none, 1 relu, 2 gelu-tanh. OUTBF: bf16 out. SCALEQ: cols<512 *= QSCALE.
// ---------------------------------------------------------------------------
template <int ACT, int OUTBF, int SCALEQ>
__global__ __launch_bounds__(256) void gemm_bf16(
    const unsigned short* __restrict__ A, const unsigned short* __restrict__ W,
    const float* __restrict__ bias, void* __restrict__ Cout,
    int M, int N, int K) {
  __shared__ unsigned short As[64 * 32];
  __shared__ unsigned short Bs[128 * 32];
  const int t = threadIdx.x;
  const int w = t >> 6, lane = t & 63;
  const int r = lane & 15, g = lane >> 4;
  const int wm = w >> 1, wn = w & 1;
  const int m0 = blockIdx.y * 64, n0 = blockIdx.x * 128;

  f32x4 acc[2][4];
#pragma unroll
  for (int mi = 0; mi < 2; ++mi)
#pragma unroll
    for (int ni = 0; ni < 4; ++ni) acc[mi][ni] = (f32x4){0.f, 0.f, 0.f, 0.f};

  for (int k0 = 0; k0 < K; k0 += 32) {
    {  // A tile: 256 chunks of 16B, one per thread
      int row = t >> 2, seg = t & 3;
      const unsigned short* ga = A + (size_t)(m0 + row) * K + k0 + seg * 8;
      __builtin_amdgcn_global_load_lds(
          (const __attribute__((address_space(1))) uint32_t*)ga,
          (__attribute__((address_space(3))) uint32_t*)&As[t * 8], 16, 0, 0);
    }
#pragma unroll
    for (int ii = 0; ii < 2; ++ii) {  // B tile: 512 chunks, two per thread
      int c = t + 256 * ii;
      int row = c >> 2, seg = c & 3;
      const unsigned short* gb = W + (size_t)(n0 + row) * K + k0 + seg * 8;
      __builtin_amdgcn_global_load_lds(
          (const __attribute__((address_space(1))) uint32_t*)gb,
          (__attribute__((address_space(3))) uint32_t*)&Bs[c * 8], 16, 0, 0);
    }
    __syncthreads();
    s16x8 af[2], bf[4];
#pragma unroll
    for (int mi = 0; mi < 2; ++mi)
      af[mi] = *(const s16x8*)&As[(wm * 32 + mi * 16 + r) * 32 + g * 8];
#pragma unroll
    for (int ni = 0; ni < 4; ++ni)
      bf[ni] = *(const s16x8*)&Bs[(wn * 64 + ni * 16 + r) * 32 + g * 8];
#pragma unroll
    for (int mi = 0; mi < 2; ++mi)
#pragma unroll
      for (int ni = 0; ni < 4; ++ni)
        acc[mi][ni] = __builtin_amdgcn_mfma_f32_16x16x32_bf16(
            af[mi], bf[ni], acc[mi][ni], 0, 0, 0);
    __syncthreads();
  }

#pragma unroll
  for (int ni = 0; ni < 4; ++ni) {
    const int col = n0 + wn * 64 + ni * 16 + r;
    const float bv = bias[col];
#pragma unroll
    for (int mi = 0; mi < 2; ++mi) {
#pragma unroll
      for (int rg = 0; rg < 4; ++rg) {
        const int row = m0 + wm * 32 + mi * 16 + g * 4 + rg;
        float v = acc[mi][ni][rg] + bv;
        if (ACT == 1) v = fmaxf(v, 0.f);
        if (ACT == 2) {
          float u = 0.7978845608028654f * (v + 0.044715f * v * v * v);
          float e = __expf(2.f * u);
          float th = 1.f - 2.f / (e + 1.f);
          v = 0.5f * v * (1.f + th);
        }
        if (SCALEQ && col < 512) v *= QSCALE;
        if (OUTBF)
          ((unsigned short*)Cout)[(size_t)row * N + col] = f2bf(v);
        else
          ((float*)Cout)[(size_t)row * N + col] = v;
      }
    }
  }
}

// ---------------------------------------------------------------------------
// 3) V transpose per (b,h): V[(b*S+s)*vstride + h*32+d] -> VT[(b*16+h)*32+d][s]
// ---------------------------------------------------------------------------
template <int S>
__global__ __launch_bounds__(256) void vtrans_kernel(
    const unsigned short* __restrict__ V, int vstride,
    unsigned short* __restrict__ VT) {
  const int b = blockIdx.z, h = blockIdx.y, s0 = blockIdx.x * 64;
  const int t = threadIdx.x;
  __shared__ unsigned short tile[64 * 40];
  {
    int i = t >> 2, seg = t & 3;
    *(uint4*)&tile[i * 40 + seg * 8] =
        *(const uint4*)&V[((size_t)(b * S + s0 + i)) * vstride + h * 32 + seg * 8];
  }
  __syncthreads();
  {
    int d = t >> 3, j = t & 7;
    unsigned short vals[8];
#pragma unroll
    for (int u = 0; u < 8; ++u) vals[u] = tile[(j * 8 + u) * 40 + d];
    *(uint4*)&VT[((size_t)((b * 16 + h) * 32 + d)) * S + s0 + j * 8] =
        *(const uint4*)vals;
  }
}

// ---------------------------------------------------------------------------
// 4) MFMA flash attention. Block = (128 q-rows, head, batch), 8 waves x 16 rows.
//    Q pre-scaled by scale*log2e -> softmax in exp2 domain.
//    K [128][40] LDS; VT [32][136] chunk-swizzled; P per-wave [16][136] swizzled.
//    Swizzle: 16B chunk index ^= (row + row/8) & 7  (rows 8 apart must differ).
// ---------------------------------------------------------------------------
template <int S>
__global__ __launch_bounds__(512) void attn_mfma(
    const unsigned short* __restrict__ Q, int qstride,
    const unsigned short* __restrict__ K, int kstride,
    const unsigned short* __restrict__ VT, unsigned short* __restrict__ O) {
  constexpr int NT = S / 128;
  __shared__ unsigned short Kl[128 * 40];
  __shared__ unsigned short Vl[32 * 136];
  __shared__ unsigned short Pl[8][16 * 136];
  const int t = threadIdx.x;
  const int w = t >> 6, lane = t & 63;
  const int r = lane & 15, g = lane >> 4;
  const int qt = blockIdx.x, h = blockIdx.y, b = blockIdx.z;
  const int q0 = qt * 128 + w * 16;

  s16x8 qa = *(const s16x8*)&Q[((size_t)(b * 1024 + q0 + r)) * qstride + h * 32 + g * 8];

  f32x4 o[2];
  o[0] = (f32x4){0.f, 0.f, 0.f, 0.f};
  o[1] = (f32x4){0.f, 0.f, 0.f, 0.f};
  float mr[4] = {-1e30f, -1e30f, -1e30f, -1e30f};
  float lr[4] = {0.f, 0.f, 0.f, 0.f};

  const int xvr = (r + (r >> 3)) & 7;          // P-read / Vl row r swizzle
  const int xv1 = (r + (r >> 3) + 2) & 7;      // Vl row 16+r swizzle

  for (int nt = 0; nt < NT; ++nt) {
    const int kv0 = nt * 128;
    {  // stage K tile: 512 chunks, 1 per thread (no swizzle, stride 40)
      int row = t >> 2, seg = t & 3;
      *(uint4*)&Kl[row * 40 + seg * 8] =
          *(const uint4*)&K[((size_t)(b * S + kv0 + row)) * kstride + h * 32 + seg * 8];
    }
    {  // stage VT tile: 512 chunks, 1 per thread, chunk-swizzled
      int d = t >> 4, sc = t & 15;
      int xv = (d + (d >> 3)) & 7;
      *(uint4*)&Vl[d * 136 + ((sc ^ xv) << 3)] =
          *(const uint4*)&VT[((size_t)((b * 16 + h) * 32 + d)) * S + kv0 + sc * 8];
    }
    __syncthreads();

    // QK^T: s[nb] = rows q (16), cols kv = nb*16 + r
    f32x4 s[8];
#pragma unroll
    for (int nb = 0; nb < 8; ++nb) {
      s16x8 kb = *(const s16x8*)&Kl[(nb * 16 + r) * 40 + g * 8];
      s[nb] = __builtin_amdgcn_mfma_f32_16x16x32_bf16(
          qa, kb, (f32x4){0.f, 0.f, 0.f, 0.f}, 0, 0, 0);
    }

    // online softmax (exp2 domain); lane's rows: q = g*4 + rg, col = nb*16 + r
#pragma unroll
    for (int rg = 0; rg < 4; ++rg) {
      const int row = g * 4 + rg;
      const int xv = (row + (row >> 3)) & 7;
      float tm = s[0][rg];
#pragma unroll
      for (int nb = 1; nb < 8; ++nb) tm = fmaxf(tm, s[nb][rg]);
      tm = fmaxf(tm, __shfl_xor(tm, 1));
      tm = fmaxf(tm, __shfl_xor(tm, 2));
      tm = fmaxf(tm, __shfl_xor(tm, 4));
      tm = fmaxf(tm, __shfl_xor(tm, 8));
      const float mold = mr[rg];
      const float mnew = fmaxf(mold, tm);
      const float corr = __builtin_amdgcn_exp2f(mold - mnew);
      float ps = 0.f;
#pragma unroll
      for (int nb = 0; nb < 8; ++nb) {
        float p = __builtin_amdgcn_exp2f(s[nb][rg] - mnew);
        ps += p;
        int e = nb * 16 + r;
        Pl[w][row * 136 + (((e >> 3) ^ xv) << 3) + (e & 7)] = f2bf(p);
      }
      ps += __shfl_xor(ps, 1);
      ps += __shfl_xor(ps, 2);
      ps += __shfl_xor(ps, 4);
      ps += __shfl_xor(ps, 8);
      lr[rg] = lr[rg] * corr + ps;
      mr[rg] = mnew;
      o[0][rg] *= corr;
      o[1][rg] *= corr;
    }

    // PV: O[q][d] += P[q][kv] * V[kv][d]
#pragma unroll
    for (int ks = 0; ks < 4; ++ks) {
      s16x8 pa  = *(const s16x8*)&Pl[w][r * 136 + (((ks * 4 + g) ^ xvr) << 3)];
      s16x8 vb0 = *(const s16x8*)&Vl[r * 136 + (((ks * 4 + g) ^ xvr) << 3)];
      s16x8 vb1 = *(const s16x8*)&Vl[(16 + r) * 136 + (((ks * 4 + g) ^ xv1) << 3)];
      o[0] = __builtin_amdgcn_mfma_f32_16x16x32_bf16(pa, vb0, o[0], 0, 0, 0);
      o[1] = __builtin_amdgcn_mfma_f32_16x16x32_bf16(pa, vb1, o[1], 0, 0, 0);
    }
    __syncthreads();
  }

#pragma unroll
  for (int rg = 0; rg < 4; ++rg) {
    const float inv = 1.f / lr[rg];
    const size_t row = (size_t)(b * 1024 + q0 + g * 4 + rg);
    O[row * 512 + h * 32 + r]      = f2bf(o[0][rg] * inv);
    O[row * 512 + h * 32 + 16 + r] = f2bf(o[1][rg] * inv);
  }
}

// ---------------------------------------------------------------------------
// 5) LayerNorm(X + A) * g + b.  XBF/ABF: inputs bf16. MODE 0: bf16 out;
//    MODE 1: f32 out transposed to [b][c][l].
// ---------------------------------------------------------------------------
template <int XBF, int ABF, int MODE>
__global__ __launch_bounds__(256) void ln_kernel(
    const void* __restrict__ X, const void* __restrict__ A,
    const float* __restrict__ gw, const float* __restrict__ bw,
    void* __restrict__ O) {
  const int rr = blockIdx.x;
  const int t = threadIdx.x;
  const size_t base = (size_t)rr * 512;
  float x0, x1, a0, a1;
  if (XBF) {
    x0 = bf2f(((const unsigned short*)X)[base + t]);
    x1 = bf2f(((const unsigned short*)X)[base + t + 256]);
  } else {
    x0 = ((const float*)X)[base + t];
    x1 = ((const float*)X)[base + t + 256];
  }
  if (ABF) {
    a0 = bf2f(((const unsigned short*)A)[base + t]);
    a1 = bf2f(((const unsigned short*)A)[base + t + 256]);
  } else {
    a0 = ((const float*)A)[base + t];
    a1 = ((const float*)A)[base + t + 256];
  }
  float v0 = x0 + a0;
  float v1 = x1 + a1;
  __shared__ float wsum[4];
  float s = v0 + v1;
#pragma unroll
  for (int of = 32; of; of >>= 1) s += __shfl_down(s, of);
  if ((t & 63) == 0) wsum[t >> 6] = s;
  __syncthreads();
  const float mean = (wsum[0] + wsum[1] + wsum[2] + wsum[3]) * (1.f / 512.f);
  __syncthreads();
  float d0 = v0 - mean, d1 = v1 - mean;
  float s2 = d0 * d0 + d1 * d1;
#pragma unroll
  for (int of = 32; of; of >>= 1) s2 += __shfl_down(s2, of);
  if ((t & 63) == 0) wsum[t >> 6] = s2;
  __syncthreads();
  const float var = (wsum[0] + wsum[1] + wsum[2] + wsum[3]) * (1.f / 512.f);
  const float rstd = rsqrtf(var + 1e-5f);
  float o0 = d0 * rstd * gw[t] + bw[t];
  float o1 = d1 * rstd * gw[t + 256] + bw[t + 256];
  if (MODE == 0) {
    ((unsigned short*)O)[base + t] = f2bf(o0);
    ((unsigned short*)O)[base + t + 256] = f2bf(o1);
  } else {
    int b = rr >> 10, l = rr & 1023;
    ((float*)O)[((size_t)(b * 512) + t) * 1024 + l] = o0;
    ((float*)O)[((size_t)(b * 512) + t + 256) * 1024 + l] = o1;
  }
}

// ---------------------------------------------------------------------------
extern "C" void kernel_launch(void* const* d_in, const int* in_sizes, int n_in,
                              void* d_out, int out_size, void* d_ws, size_t ws_size,
                              hipStream_t stream) {
  const float* x      = (const float*)d_in[0];
  const float* gf     = (const float*)d_in[1];
  const float* conv_w = (const float*)d_in[2];
  const float* conv_b = (const float*)d_in[3];
  const float* sWq = (const float*)d_in[4],  *sbq = (const float*)d_in[5];
  const float* sWk = (const float*)d_in[6],  *sbk = (const float*)d_in[7];
  const float* sWv = (const float*)d_in[8],  *sbv = (const float*)d_in[9];
  const float* sWo = (const float*)d_in[10], *sbo = (const float*)d_in[11];
  const float* cWq = (const float*)d_in[12], *cbq = (const float*)d_in[13];
  const float* cWk = (const float*)d_in[14], *cbk = (const float*)d_in[15];
  const float* cWv = (const float*)d_in[16], *cbv = (const float*)d_in[17];
  const float* cWo = (const float*)d_in[18], *cbo = (const float*)d_in[19];
  const float* fw1 = (const float*)d_in[20], *fb1 = (const float*)d_in[21];
  const float* fw2 = (const float*)d_in[22], *fb2 = (const float*)d_in[23];
  const float* ln1_g = (const float*)d_in[24], *ln1_b = (const float*)d_in[25];
  const float* ln2_g = (const float*)d_in[26], *ln2_b = (const float*)d_in[27];
  const float* ln3_g = (const float*)d_in[28], *ln3_b = (const float*)d_in[29];
  float* out = (float*)d_out;

  // bf16 conversion pool (ushort element offsets):
  unsigned short* bfp = (unsigned short*)d_ws;
  unsigned short* conv_wb = bfp + 0;
  unsigned short* sWqb = bfp + 262144;   // [Wq;Wk;Wv] contiguous = fused QKV W
  unsigned short* cWqb = bfp + 1310720;
  unsigned short* cWkb = bfp + 1572864;  // [cWk;cWv] contiguous = fused cKV W
  unsigned short* cWob = bfp + 2097152;
  unsigned short* sWob = bfp + 1048576;
  unsigned short* fw1b = bfp + 2359296, *fw2b = bfp + 3407872;
  unsigned short* xbf  = bfp + 4456448;  // pool ends at el 6,553,600

  unsigned short* SC   = bfp + 6553600;
  unsigned short* qkvb = SC;                  // 6,291,456  [4096][1536]
  unsigned short* ckvb = SC + 6291456;        // 2,097,152  [2048][1024]
  unsigned short* qcb  = SC + 8388608;        // 2,097,152  (statTb overlays)
  unsigned short* vtb  = SC + 10485760;       // 2,097,152
  unsigned short* ctxb = SC + 12582912;       // 2,097,152  (crossb overlays)
  unsigned short* projb= SC + 14680064;       // 2,097,152  (biasf overlays head)
  unsigned short* hbf  = SC + 16777216;       // 2,097,152
  unsigned short* h2bf = SC + 18874368;       // 2,097,152  (SC ends 20,971,520)
  unsigned short* statTb = qcb;
  unsigned short* crossb = ctxb;
  unsigned short* midb   = qkvb;              // 8,388,608 = qkvb+ckvb (dead then)
  float* biasf = (float*)projb;               // [1536 qkv | 1024 ckv] f32

  convert_bf16_kernel<<<3200, 256, 0, stream>>>(
      conv_w, sWq, sWk, sWv, sWo, cWq, cWk, cWv, cWo, fw1, fw2, x, bfp);
  window_stat_kernel<<<4096, 256, 0, stream>>>(gf, statTb);
  biascat_kernel<<<10, 256, 0, stream>>>(sbq, sbk, sbv, cbk, cbv, biasf);

  // pointwise conv + relu -> cross tokens [2048][512]
  gemm_bf16<1, 1, 0><<<dim3(4, 32), 256, 0, stream>>>(
      statTb, conv_wb, conv_b, crossb, 2048, 512, 512);
  // fused self QKV [4096][1536], Q cols pre-scaled
  gemm_bf16<0, 1, 1><<<dim3(12, 64), 256, 0, stream>>>(
      xbf, sWqb, biasf, qkvb, 4096, 1536, 512);
  // fused cross KV [2048][1024]
  gemm_bf16<0, 1, 0><<<dim3(8, 32), 256, 0, stream>>>(
      crossb, cWkb, biasf + 1536, ckvb, 2048, 1024, 512);

  // self-attention
  vtrans_kernel<1024><<<dim3(16, 16, 4), 256, 0, stream>>>(qkvb + 1024, 1536, vtb);
  attn_mfma<1024><<<dim3(8, 16, 4), 512, 0, stream>>>(
      qkvb, 1536, qkvb + 512, 1536, vtb, ctxb);
  gemm_bf16<0, 1, 0><<<dim3(4, 64), 256, 0, stream>>>(
      ctxb, sWob, sbo, projb, 4096, 512, 512);
  ln_kernel<0, 1, 0><<<4096, 256, 0, stream>>>(x, projb, ln1_g, ln1_b, hbf);

  // cross-attention (K/V from conv tokens, S=512)
  gemm_bf16<0, 1, 1><<<dim3(4, 64), 256, 0, stream>>>(
      hbf, cWqb, cbq, qcb, 4096, 512, 512);
  vtrans_kernel<512><<<dim3(8, 16, 4), 256, 0, stream>>>(ckvb + 512, 1024, vtb);
  attn_mfma<512><<<dim3(8, 16, 4), 512, 0, stream>>>(
      qcb, 512, ckvb, 1024, vtb, ctxb);
  gemm_bf16<0, 1, 0><<<dim3(4, 64), 256, 0, stream>>>(
      ctxb, cWob, cbo, projb, 4096, 512, 512);
  ln_kernel<1, 1, 0><<<4096, 256, 0, stream>>>(hbf, projb, ln2_g, ln2_b, h2bf);

  // FFN + final LN (transposed f32 out)
  gemm_bf16<2, 1, 0><<<dim3(16, 64), 256, 0, stream>>>(
      h2bf, fw1b, fb1, midb, 4096, 2048, 512);
  gemm_bf16<0, 1, 0><<<dim3(4, 64), 256, 0, stream>>>(
      midb, fw2b, fb2, projb, 4096, 512, 2048);
  ln_kernel<1, 1, 1><<<4096, 256, 0, stream>>>(h2bf, projb, ln3_g, ln3_b, out);
}

// Round 5
// 380.275 us; speedup vs baseline: 6.9273x; 1.1006x over previous
//
#include <hip/hip_runtime.h>
#include <stdint.h>
#include <math.h>

// B=4, L1=1024, D=512, H=16, DH=32, L=8192, win=16, NW=512, DFF=2048

typedef short  s16x8 __attribute__((ext_vector_type(8)));
typedef float  f32x4 __attribute__((ext_vector_type(4)));

__device__ inline unsigned short f2bf(float f) {
  uint32_t u = __builtin_bit_cast(uint32_t, f);
  u += 0x7fffu + ((u >> 16) & 1u);
  return (unsigned short)(u >> 16);
}
__device__ inline float bf2f(unsigned short h) {
  uint32_t u = ((uint32_t)h) << 16;
  return __builtin_bit_cast(float, u);
}
// pack 2 f32 -> 2 bf16 in one VALU op (src0 -> low half)
__device__ inline uint32_t cvtpk_bf16(float lo, float hi) {
  uint32_t r;
  asm("v_cvt_pk_bf16_f32 %0, %1, %2" : "=v"(r) : "v"(lo), "v"(hi));
  return r;
}

// scale(1/sqrt(32)) * log2(e): folded into Q so softmax is pure exp2
#define QSCALE 0.25503486611627154f

// ---------------------------------------------------------------------------
// 0) fused f32 -> bf16 conversion of x + all weights into one contiguous pool
// ---------------------------------------------------------------------------
__global__ __launch_bounds__(256) void convert_bf16_kernel(
    const float* s0, const float* s1, const float* s2, const float* s3,
    const float* s4, const float* s5, const float* s6, const float* s7,
    const float* s8, const float* s9, const float* s10, const float* s11,
    unsigned short* dst) {
  const size_t cum[13] = {0, 262144, 524288, 786432, 1048576, 1310720,
                          1572864, 1835008, 2097152, 2359296, 3407872,
                          4456448, 6553600};
  const float* srcs[12] = {s0, s1, s2, s3, s4, s5, s6, s7, s8, s9, s10, s11};
  size_t e0 = ((size_t)blockIdx.x * 256 + threadIdx.x) * 8;
  int seg = 0;
  while (e0 >= cum[seg + 1]) ++seg;
  const float* sp = srcs[seg] + (e0 - cum[seg]);
  float4 a = *(const float4*)sp;
  float4 b = *(const float4*)(sp + 4);
  unsigned short o[8] = {f2bf(a.x), f2bf(a.y), f2bf(a.z), f2bf(a.w),
                         f2bf(b.x), f2bf(b.y), f2bf(b.z), f2bf(b.w)};
  *(uint4*)&dst[e0] = *(const uint4*)o;
}

// ---------------------------------------------------------------------------
// 1) window stat -> bf16, transposed: statT[b][n][c] = |max-min| over window
// ---------------------------------------------------------------------------
__global__ __launch_bounds__(256) void window_stat_kernel(
    const float* __restrict__ gf, unsigned short* __restrict__ statT) {
  int gidx = blockIdx.x * 256 + threadIdx.x;
  int c = gidx & 511;
  int n = (gidx >> 9) & 511;
  int b = gidx >> 18;
  const float4* p = (const float4*)(gf + ((size_t)(b * 512 + c) << 13) + n * 16);
  float4 w0 = p[0], w1 = p[1], w2 = p[2], w3 = p[3];
  float mx = w0.x, mn = w0.x;
  float vals[15] = {w0.y, w0.z, w0.w, w1.x, w1.y, w1.z, w1.w,
                    w2.x, w2.y, w2.z, w2.w, w3.x, w3.y, w3.z, w3.w};
#pragma unroll
  for (int i = 0; i < 15; ++i) {
    mx = fmaxf(mx, vals[i]);
    mn = fminf(mn, vals[i]);
  }
  statT[((size_t)(b * 512 + n) << 9) + c] = f2bf(mx - mn);
}

// ---------------------------------------------------------------------------
// 1b) concat QKV / cross-KV biases into one f32 buffer [1536 | 1024]
// ---------------------------------------------------------------------------
__global__ __launch_bounds__(256) void biascat_kernel(
    const float* __restrict__ sbq, const float* __restrict__ sbk,
    const float* __restrict__ sbv, const float* __restrict__ cbk,
    const float* __restrict__ cbv, float* __restrict__ dst) {
  int i = blockIdx.x * 256 + threadIdx.x;  // 2560 total
  float v;
  if (i < 512) v = sbq[i];
  else if (i < 1024) v = sbk[i - 512];
  else if (i < 1536) v = sbv[i - 1024];
  else if (i < 2048) v = cbk[i - 1536];
  else v = cbv[i - 2048];
  dst[i] = v;
}

// ---------------------------------------------------------------------------
// 2) bf16 MFMA GEMM, 2-phase pipelined: C[m,n] = act(sum_k A[m,k]W[n,k]+b[n])
//    BM=64, BN=128, BK=32, double-buffered LDS, 4 waves, per-wave 32x64.
//    STAGE(next) issued BEFORE compute(cur); ONE barrier per K-step.
// ---------------------------------------------------------------------------
template <int ACT, int OUTBF, int SCALEQ>
__global__ __launch_bounds__(256) void gemm_bf16(
    const unsigned short* __restrict__ A, const unsigned short* __restrict__ W,
    const float* __restrict__ bias, void* __restrict__ Cout,
    int M, int N, int K) {
  __shared__ __align__(16) unsigned short As[2][64 * 32];
  __shared__ __align__(16) unsigned short Bs[2][128 * 32];
  const int t = threadIdx.x;
  const int w = t >> 6, lane = t & 63;
  const int r = lane & 15, g = lane >> 4;
  const int wm = w >> 1, wn = w & 1;
  const int m0 = blockIdx.y * 64, n0 = blockIdx.x * 128;

  auto STAGE = [&](int buf, int k0) {
    {  // A tile: 256 chunks of 16B, one per thread
      int row = t >> 2, seg = t & 3;
      const unsigned short* ga = A + (size_t)(m0 + row) * K + k0 + seg * 8;
      __builtin_amdgcn_global_load_lds(
          (const __attribute__((address_space(1))) uint32_t*)ga,
          (__attribute__((address_space(3))) uint32_t*)&As[buf][t * 8], 16, 0, 0);
    }
#pragma unroll
    for (int ii = 0; ii < 2; ++ii) {  // B tile: 512 chunks, two per thread
      int c = t + 256 * ii;
      int row = c >> 2, seg = c & 3;
      const unsigned short* gb = W + (size_t)(n0 + row) * K + k0 + seg * 8;
      __builtin_amdgcn_global_load_lds(
          (const __attribute__((address_space(1))) uint32_t*)gb,
          (__attribute__((address_space(3))) uint32_t*)&Bs[buf][c * 8], 16, 0, 0);
    }
  };

  f32x4 acc[2][4];
#pragma unroll
  for (int mi = 0; mi < 2; ++mi)
#pragma unroll
    for (int ni = 0; ni < 4; ++ni) acc[mi][ni] = (f32x4){0.f, 0.f, 0.f, 0.f};

  STAGE(0, 0);
  __syncthreads();  // drains vmcnt(0) before barrier (compiler-emitted)
  int cur = 0;
  for (int k0 = 0; k0 < K; k0 += 32) {
    if (k0 + 32 < K) STAGE(cur ^ 1, k0 + 32);  // prefetch next tile
    s16x8 af[2], bf[4];
#pragma unroll
    for (int mi = 0; mi < 2; ++mi)
      af[mi] = *(const s16x8*)&As[cur][(wm * 32 + mi * 16 + r) * 32 + g * 8];
#pragma unroll
    for (int ni = 0; ni < 4; ++ni)
      bf[ni] = *(const s16x8*)&Bs[cur][(wn * 64 + ni * 16 + r) * 32 + g * 8];
#pragma unroll
    for (int mi = 0; mi < 2; ++mi)
#pragma unroll
      for (int ni = 0; ni < 4; ++ni)
        acc[mi][ni] = __builtin_amdgcn_mfma_f32_16x16x32_bf16(
            af[mi], bf[ni], acc[mi][ni], 0, 0, 0);
    __syncthreads();  // next stage landed; all waves done reading cur
    cur ^= 1;
  }

#pragma unroll
  for (int ni = 0; ni < 4; ++ni) {
    const int col = n0 + wn * 64 + ni * 16 + r;
    const float bv = bias[col];
#pragma unroll
    for (int mi = 0; mi < 2; ++mi) {
#pragma unroll
      for (int rg = 0; rg < 4; ++rg) {
        const int row = m0 + wm * 32 + mi * 16 + g * 4 + rg;
        float v = acc[mi][ni][rg] + bv;
        if (ACT == 1) v = fmaxf(v, 0.f);
        if (ACT == 2) {
          float u = 0.7978845608028654f * (v + 0.044715f * v * v * v);
          float e = __expf(2.f * u);
          float th = 1.f - 2.f / (e + 1.f);
          v = 0.5f * v * (1.f + th);
        }
        if (SCALEQ && col < 512) v *= QSCALE;
        if (OUTBF)
          ((unsigned short*)Cout)[(size_t)row * N + col] = f2bf(v);
        else
          ((float*)Cout)[(size_t)row * N + col] = v;
      }
    }
  }
}

// ---------------------------------------------------------------------------
// 3) V transpose per (b,h): V[(b*S+s)*vstride + h*32+d] -> VT[(b*16+h)*32+d][s]
// ---------------------------------------------------------------------------
template <int S>
__global__ __launch_bounds__(256) void vtrans_kernel(
    const unsigned short* __restrict__ V, int vstride,
    unsigned short* __restrict__ VT) {
  const int b = blockIdx.z, h = blockIdx.y, s0 = blockIdx.x * 64;
  const int t = threadIdx.x;
  __shared__ unsigned short tile[64 * 40];
  {
    int i = t >> 2, seg = t & 3;
    *(uint4*)&tile[i * 40 + seg * 8] =
        *(const uint4*)&V[((size_t)(b * S + s0 + i)) * vstride + h * 32 + seg * 8];
  }
  __syncthreads();
  {
    int d = t >> 3, j = t & 7;
    unsigned short vals[8];
#pragma unroll
    for (int u = 0; u < 8; ++u) vals[u] = tile[(j * 8 + u) * 40 + d];
    *(uint4*)&VT[((size_t)((b * 16 + h) * 32 + d)) * S + s0 + j * 8] =
        *(const uint4*)vals;
  }
}

// ---------------------------------------------------------------------------
// 4) MFMA flash attention, SWAPPED operands. Block = (128 q, head, batch),
//    8 waves x 16 q-rows. S_kvq = mfma(K, Q): lane (r,g) owns q-row r,
//    kv = nb*16 + g*4 + rg. Softmax in-lane (+2 shfl). P packed via
//    v_cvt_pk_bf16_f32, 8 conflict-free ds_write_b64 per tile.
//    PV: O^T = mfma(VT, P^T). All LDS strides 40/136 el (diagonal, uniform).
// ---------------------------------------------------------------------------
template <int S>
__global__ __launch_bounds__(512) void attn_mfma(
    const unsigned short* __restrict__ Q, int qstride,
    const unsigned short* __restrict__ K, int kstride,
    const unsigned short* __restrict__ VT, unsigned short* __restrict__ O) {
  constexpr int NT = S / 128;
  __shared__ __align__(16) unsigned short Kl[128 * 40];
  __shared__ __align__(16) unsigned short Vl[32 * 136];
  __shared__ __align__(16) unsigned short Pl[8][16 * 136];
  const int t = threadIdx.x;
  const int w = t >> 6, lane = t & 63;
  const int r = lane & 15, g = lane >> 4;
  const int qt = blockIdx.x, h = blockIdx.y, b = blockIdx.z;
  const int q0 = qt * 128 + w * 16;

  // Q as B-frag: lane (r,g) holds Q[q0+r][h*32 + g*8 ..+7] (pre-scaled)
  s16x8 qa = *(const s16x8*)&Q[((size_t)(b * 1024 + q0 + r)) * qstride + h * 32 + g * 8];

  f32x4 o0 = (f32x4){0.f, 0.f, 0.f, 0.f};
  f32x4 o1 = (f32x4){0.f, 0.f, 0.f, 0.f};
  float m = -1e30f, l = 0.f;

  for (int nt = 0; nt < NT; ++nt) {
    const int kv0 = nt * 128;
    {  // stage K tile [128][40]: 512 chunks, 1 per thread
      int row = t >> 2, seg = t & 3;
      *(uint4*)&Kl[row * 40 + seg * 8] =
          *(const uint4*)&K[((size_t)(b * S + kv0 + row)) * kstride + h * 32 + seg * 8];
    }
    {  // stage VT tile [32][136]: 512 chunks, 1 per thread (NO swizzle)
      int d = t >> 4, sc = t & 15;
      *(uint4*)&Vl[d * 136 + sc * 8] =
          *(const uint4*)&VT[((size_t)((b * 16 + h) * 32 + d)) * S + kv0 + sc * 8];
    }
    __syncthreads();

    // S^T = K·Q^T: s[nb][rg] = S[kv = nb*16+g*4+rg][q = r]
    f32x4 s[8];
#pragma unroll
    for (int nb = 0; nb < 8; ++nb) {
      s16x8 ka = *(const s16x8*)&Kl[(nb * 16 + r) * 40 + g * 8];
      s[nb] = __builtin_amdgcn_mfma_f32_16x16x32_bf16(
          ka, qa, (f32x4){0.f, 0.f, 0.f, 0.f}, 0, 0, 0);
    }

    // online softmax for q-row r (exp2 domain), in-lane + 2 shuffles
    float tm = -1e30f;
#pragma unroll
    for (int nb = 0; nb < 8; ++nb) {
      float a01 = fmaxf(s[nb][0], s[nb][1]);
      float a23 = fmaxf(s[nb][2], s[nb][3]);
      tm = fmaxf(tm, fmaxf(a01, a23));
    }
    tm = fmaxf(tm, __shfl_xor(tm, 16));
    tm = fmaxf(tm, __shfl_xor(tm, 32));
    const float mnew = fmaxf(m, tm);
    const float corr = __builtin_amdgcn_exp2f(m - mnew);
    float ps = 0.f;
#pragma unroll
    for (int nb = 0; nb < 8; ++nb) {
      float p0 = __builtin_amdgcn_exp2f(s[nb][0] - mnew);
      float p1 = __builtin_amdgcn_exp2f(s[nb][1] - mnew);
      float p2 = __builtin_amdgcn_exp2f(s[nb][2] - mnew);
      float p3 = __builtin_amdgcn_exp2f(s[nb][3] - mnew);
      ps += (p0 + p1) + (p2 + p3);
      uint2 pv;
      pv.x = cvtpk_bf16(p0, p1);
      pv.y = cvtpk_bf16(p2, p3);
      *(uint2*)&Pl[w][r * 136 + nb * 16 + g * 4] = pv;  // own q-row, b64
    }
    ps += __shfl_xor(ps, 16);
    ps += __shfl_xor(ps, 32);
    l = l * corr + ps;
    m = mnew;
#pragma unroll
    for (int rg = 0; rg < 4; ++rg) { o0[rg] *= corr; o1[rg] *= corr; }

    // O^T[d][q] += VT[d][kv] · P^T[kv][q]  (Pl wave-private; lgkm dep in-wave)
#pragma unroll
    for (int ks = 0; ks < 4; ++ks) {
      s16x8 va0 = *(const s16x8*)&Vl[r * 136 + ks * 32 + g * 8];
      s16x8 va1 = *(const s16x8*)&Vl[(16 + r) * 136 + ks * 32 + g * 8];
      s16x8 pb  = *(const s16x8*)&Pl[w][r * 136 + ks * 32 + g * 8];
      o0 = __builtin_amdgcn_mfma_f32_16x16x32_bf16(va0, pb, o0, 0, 0, 0);
      o1 = __builtin_amdgcn_mfma_f32_16x16x32_bf16(va1, pb, o1, 0, 0, 0);
    }
    __syncthreads();
  }

  // lane (r,g): O[q = q0+r][d = g*4+rg (+16)] ; pack 4 consecutive d -> b64
  const float inv = 1.f / l;
  const size_t row = (size_t)(b * 1024 + q0 + r);
  uint2 w0, w1;
  w0.x = cvtpk_bf16(o0[0] * inv, o0[1] * inv);
  w0.y = cvtpk_bf16(o0[2] * inv, o0[3] * inv);
  w1.x = cvtpk_bf16(o1[0] * inv, o1[1] * inv);
  w1.y = cvtpk_bf16(o1[2] * inv, o1[3] * inv);
  *(uint2*)&O[row * 512 + h * 32 + g * 4]      = w0;
  *(uint2*)&O[row * 512 + h * 32 + 16 + g * 4] = w1;
}

// ---------------------------------------------------------------------------
// 5) LayerNorm(X + A) * g + b.  XBF/ABF: inputs bf16. MODE 0: bf16 out;
//    MODE 1: f32 out transposed to [b][c][l].
// ---------------------------------------------------------------------------
template <int XBF, int ABF, int MODE>
__global__ __launch_bounds__(256) void ln_kernel(
    const void* __restrict__ X, const void* __restrict__ A,
    const float* __restrict__ gw, const float* __restrict__ bw,
    void* __restrict__ O) {
  const int rr = blockIdx.x;
  const int t = threadIdx.x;
  const size_t base = (size_t)rr * 512;
  float x0, x1, a0, a1;
  if (XBF) {
    x0 = bf2f(((const unsigned short*)X)[base + t]);
    x1 = bf2f(((const unsigned short*)X)[base + t + 256]);
  } else {
    x0 = ((const float*)X)[base + t];
    x1 = ((const float*)X)[base + t + 256];
  }
  if (ABF) {
    a0 = bf2f(((const unsigned short*)A)[base + t]);
    a1 = bf2f(((const unsigned short*)A)[base + t + 256]);
  } else {
    a0 = ((const float*)A)[base + t];
    a1 = ((const float*)A)[base + t + 256];
  }
  float v0 = x0 + a0;
  float v1 = x1 + a1;
  __shared__ float wsum[4];
  float s = v0 + v1;
#pragma unroll
  for (int of = 32; of; of >>= 1) s += __shfl_down(s, of);
  if ((t & 63) == 0) wsum[t >> 6] = s;
  __syncthreads();
  const float mean = (wsum[0] + wsum[1] + wsum[2] + wsum[3]) * (1.f / 512.f);
  __syncthreads();
  float d0 = v0 - mean, d1 = v1 - mean;
  float s2 = d0 * d0 + d1 * d1;
#pragma unroll
  for (int of = 32; of; of >>= 1) s2 += __shfl_down(s2, of);
  if ((t & 63) == 0) wsum[t >> 6] = s2;
  __syncthreads();
  const float var = (wsum[0] + wsum[1] + wsum[2] + wsum[3]) * (1.f / 512.f);
  const float rstd = rsqrtf(var + 1e-5f);
  float o0 = d0 * rstd * gw[t] + bw[t];
  float o1 = d1 * rstd * gw[t + 256] + bw[t + 256];
  if (MODE == 0) {
    ((unsigned short*)O)[base + t] = f2bf(o0);
    ((unsigned short*)O)[base + t + 256] = f2bf(o1);
  } else {
    int b = rr >> 10, l = rr & 1023;
    ((float*)O)[((size_t)(b * 512) + t) * 1024 + l] = o0;
    ((float*)O)[((size_t)(b * 512) + t + 256) * 1024 + l] = o1;
  }
}

// ---------------------------------------------------------------------------
extern "C" void kernel_launch(void* const* d_in, const int* in_sizes, int n_in,
                              void* d_out, int out_size, void* d_ws, size_t ws_size,
                              hipStream_t stream) {
  const float* x      = (const float*)d_in[0];
  const float* gf     = (const float*)d_in[1];
  const float* conv_w = (const float*)d_in[2];
  const float* conv_b = (const float*)d_in[3];
  const float* sWq = (const float*)d_in[4],  *sbq = (const float*)d_in[5];
  const float* sWk = (const float*)d_in[6],  *sbk = (const float*)d_in[7];
  const float* sWv = (const float*)d_in[8],  *sbv = (const float*)d_in[9];
  const float* sWo = (const float*)d_in[10], *sbo = (const float*)d_in[11];
  const float* cWq = (const float*)d_in[12], *cbq = (const float*)d_in[13];
  const float* cWk = (const float*)d_in[14], *cbk = (const float*)d_in[15];
  const float* cWv = (const float*)d_in[16], *cbv = (const float*)d_in[17];
  const float* cWo = (const float*)d_in[18], *cbo = (const float*)d_in[19];
  const float* fw1 = (const float*)d_in[20], *fb1 = (const float*)d_in[21];
  const float* fw2 = (const float*)d_in[22], *fb2 = (const float*)d_in[23];
  const float* ln1_g = (const float*)d_in[24], *ln1_b = (const float*)d_in[25];
  const float* ln2_g = (const float*)d_in[26], *ln2_b = (const float*)d_in[27];
  const float* ln3_g = (const float*)d_in[28], *ln3_b = (const float*)d_in[29];
  float* out = (float*)d_out;

  // bf16 conversion pool (ushort element offsets):
  unsigned short* bfp = (unsigned short*)d_ws;
  unsigned short* conv_wb = bfp + 0;
  unsigned short* sWqb = bfp + 262144;   // [Wq;Wk;Wv] contiguous = fused QKV W
  unsigned short* cWqb = bfp + 1310720;
  unsigned short* cWkb = bfp + 1572864;  // [cWk;cWv] contiguous = fused cKV W
  unsigned short* cWob = bfp + 2097152;
  unsigned short* sWob = bfp + 1048576;
  unsigned short* fw1b = bfp + 2359296, *fw2b = bfp + 3407872;
  unsigned short* xbf  = bfp + 4456448;  // pool ends at el 6,553,600

  unsigned short* SC   = bfp + 6553600;
  unsigned short* qkvb = SC;                  // 6,291,456  [4096][1536]
  unsigned short* ckvb = SC + 6291456;        // 2,097,152  [2048][1024]
  unsigned short* qcb  = SC + 8388608;        // 2,097,152  (statTb overlays)
  unsigned short* vtb  = SC + 10485760;       // 2,097,152
  unsigned short* ctxb = SC + 12582912;       // 2,097,152  (crossb overlays)
  unsigned short* projb= SC + 14680064;       // 2,097,152  (biasf overlays head)
  unsigned short* hbf  = SC + 16777216;       // 2,097,152
  unsigned short* h2bf = SC + 18874368;       // 2,097,152  (SC ends 20,971,520)
  unsigned short* statTb = qcb;
  unsigned short* crossb = ctxb;
  unsigned short* midb   = qkvb;              // 8,388,608 = qkvb+ckvb (dead then)
  float* biasf = (float*)projb;               // [1536 qkv | 1024 ckv] f32

  convert_bf16_kernel<<<3200, 256, 0, stream>>>(
      conv_w, sWq, sWk, sWv, sWo, cWq, cWk, cWv, cWo, fw1, fw2, x, bfp);
  window_stat_kernel<<<4096, 256, 0, stream>>>(gf, statTb);
  biascat_kernel<<<10, 256, 0, stream>>>(sbq, sbk, sbv, cbk, cbv, biasf);

  // pointwise conv + relu -> cross tokens [2048][512]
  gemm_bf16<1, 1, 0><<<dim3(4, 32), 256, 0, stream>>>(
      statTb, conv_wb, conv_b, crossb, 2048, 512, 512);
  // fused self QKV [4096][1536], Q cols pre-scaled
  gemm_bf16<0, 1, 1><<<dim3(12, 64), 256, 0, stream>>>(
      xbf, sWqb, biasf, qkvb, 4096, 1536, 512);
  // fused cross KV [2048][1024]
  gemm_bf16<0, 1, 0><<<dim3(8, 32), 256, 0, stream>>>(
      crossb, cWkb, biasf + 1536, ckvb, 2048, 1024, 512);

  // self-attention
  vtrans_kernel<1024><<<dim3(16, 16, 4), 256, 0, stream>>>(qkvb + 1024, 1536, vtb);
  attn_mfma<1024><<<dim3(8, 16, 4), 512, 0, stream>>>(
      qkvb, 1536, qkvb + 512, 1536, vtb, ctxb);
  gemm_bf16<0, 1, 0><<<dim3(4, 64), 256, 0, stream>>>(
      ctxb, sWob, sbo, projb, 4096, 512, 512);
  ln_kernel<0, 1, 0><<<4096, 256, 0, stream>>>(x, projb, ln1_g, ln1_b, hbf);

  // cross-attention (K/V from conv tokens, S=512)
  gemm_bf16<0, 1, 1><<<dim3(4, 64), 256, 0, stream>>>(
      hbf, cWqb, cbq, qcb, 4096, 512, 512);
  vtrans_kernel<512><<<dim3(8, 16, 4), 256, 0, stream>>>(ckvb + 512, 1024, vtb);
  attn_mfma<512><<<dim3(8, 16, 4), 512, 0, stream>>>(
      qcb, 512, ckvb, 1024, vtb, ctxb);
  gemm_bf16<0, 1, 0><<<dim3(4, 64), 256, 0, stream>>>(
      ctxb, cWob, cbo, projb, 4096, 512, 512);
  ln_kernel<1, 1, 0><<<4096, 256, 0, stream>>>(hbf, projb, ln2_g, ln2_b, h2bf);

  // FFN + final LN (transposed f32 out)
  gemm_bf16<2, 1, 0><<<dim3(16, 64), 256, 0, stream>>>(
      h2bf, fw1b, fb1, midb, 4096, 2048, 512);
  gemm_bf16<0, 1, 0><<<dim3(4, 64), 256, 0, stream>>>(
      midb, fw2b, fb2, projb, 4096, 512, 2048);
  ln_kernel<1, 1, 1><<<4096, 256, 0, stream>>>(h2bf, projb, ln3_g, ln3_b, out);
}

// Round 6
// 351.918 us; speedup vs baseline: 7.4855x; 1.0806x over previous
//
#include <hip/hip_runtime.h>
#include <stdint.h>
#include <math.h>

// B=4, L1=1024, D=512, H=16, DH=32, L=8192, win=16, NW=512, DFF=2048

typedef short  s16x8 __attribute__((ext_vector_type(8)));
typedef float  f32x4 __attribute__((ext_vector_type(4)));

__device__ inline unsigned short f2bf(float f) {
  uint32_t u = __builtin_bit_cast(uint32_t, f);
  u += 0x7fffu + ((u >> 16) & 1u);
  return (unsigned short)(u >> 16);
}
__device__ inline float bf2f(unsigned short h) {
  uint32_t u = ((uint32_t)h) << 16;
  return __builtin_bit_cast(float, u);
}
// pack 2 f32 -> 2 bf16 in one VALU op (src0 -> low half)
__device__ inline uint32_t cvtpk_bf16(float lo, float hi) {
  uint32_t r;
  asm("v_cvt_pk_bf16_f32 %0, %1, %2" : "=v"(r) : "v"(lo), "v"(hi));
  return r;
}

// scale(1/sqrt(32)) * log2(e): folded into Q so softmax is pure exp2
#define QSCALE 0.25503486611627154f

// ---------------------------------------------------------------------------
// 0) prep: f32->bf16 weight/x pool  |  window stat (transposed)  |  bias cat
//    grid: [0,3200) convert, [3200,7296) window stat, 7296 biascat
// ---------------------------------------------------------------------------
__global__ __launch_bounds__(256) void prep_kernel(
    const float* s0, const float* s1, const float* s2, const float* s3,
    const float* s4, const float* s5, const float* s6, const float* s7,
    const float* s8, const float* s9, const float* s10, const float* s11,
    unsigned short* dst,
    const float* __restrict__ gf, unsigned short* __restrict__ statT,
    const float* __restrict__ sbq, const float* __restrict__ sbk,
    const float* __restrict__ sbv, const float* __restrict__ cbk,
    const float* __restrict__ cbv, float* __restrict__ biasf) {
  const int bid = blockIdx.x;
  const int t = threadIdx.x;
  if (bid < 3200) {
    const size_t cum[13] = {0, 262144, 524288, 786432, 1048576, 1310720,
                            1572864, 1835008, 2097152, 2359296, 3407872,
                            4456448, 6553600};
    const float* srcs[12] = {s0, s1, s2, s3, s4, s5, s6, s7, s8, s9, s10, s11};
    size_t e0 = ((size_t)bid * 256 + t) * 8;
    int seg = 0;
    while (e0 >= cum[seg + 1]) ++seg;
    const float* sp = srcs[seg] + (e0 - cum[seg]);
    float4 a = *(const float4*)sp;
    float4 b = *(const float4*)(sp + 4);
    unsigned short o[8] = {f2bf(a.x), f2bf(a.y), f2bf(a.z), f2bf(a.w),
                           f2bf(b.x), f2bf(b.y), f2bf(b.z), f2bf(b.w)};
    *(uint4*)&dst[e0] = *(const uint4*)o;
  } else if (bid < 7296) {
    int gidx = (bid - 3200) * 256 + t;
    int c = gidx & 511;
    int n = (gidx >> 9) & 511;
    int b = gidx >> 18;
    const float4* p = (const float4*)(gf + ((size_t)(b * 512 + c) << 13) + n * 16);
    float4 w0 = p[0], w1 = p[1], w2 = p[2], w3 = p[3];
    float mx = w0.x, mn = w0.x;
    float vals[15] = {w0.y, w0.z, w0.w, w1.x, w1.y, w1.z, w1.w,
                      w2.x, w2.y, w2.z, w2.w, w3.x, w3.y, w3.z, w3.w};
#pragma unroll
    for (int i = 0; i < 15; ++i) {
      mx = fmaxf(mx, vals[i]);
      mn = fminf(mn, vals[i]);
    }
    statT[((size_t)(b * 512 + n) << 9) + c] = f2bf(mx - mn);
  } else {
    for (int i = t; i < 2560; i += 256) {
      float v;
      if (i < 512) v = sbq[i];
      else if (i < 1024) v = sbk[i - 512];
      else if (i < 1536) v = sbv[i - 1024];
      else if (i < 2048) v = cbk[i - 1536];
      else v = cbv[i - 2048];
      biasf[i] = v;
    }
  }
}

// ---------------------------------------------------------------------------
// 2) bf16 MFMA GEMM, BK=64, 2-phase dbuf, T2 XOR swizzle (rule-21 pattern:
//    linear gload_lds dest + pre-swizzled global SOURCE + swizzled ds_read).
//    BM=64, BN=128, 4 waves (2x2), per-wave 32x64, 16 MFMA / K-step.
// ---------------------------------------------------------------------------
template <int ACT, int OUTBF, int SCALEQ>
__global__ __launch_bounds__(256) void gemm_bf16(
    const unsigned short* __restrict__ A, const unsigned short* __restrict__ W,
    const float* __restrict__ bias, void* __restrict__ Cout,
    int M, int N, int K) {
  __shared__ __align__(16) unsigned short As[2][64 * 64];
  __shared__ __align__(16) unsigned short Bs[2][128 * 64];
  const int t = threadIdx.x;
  const int w = t >> 6, lane = t & 63;
  const int r = lane & 15, g = lane >> 4;
  const int wm = w >> 1, wn = w & 1;
  const int m0 = blockIdx.y * 64, n0 = blockIdx.x * 128;

  auto STAGE = [&](int buf, int k0) {
#pragma unroll
    for (int ii = 0; ii < 2; ++ii) {  // A: 512 16B chunks (64 rows x 8)
      int c = t + 256 * ii;
      int row = c >> 3, sc = c & 7;
      const unsigned short* ga =
          A + (size_t)(m0 + row) * K + k0 + ((sc ^ (row & 7)) << 3);
      __builtin_amdgcn_global_load_lds(
          (const __attribute__((address_space(1))) uint32_t*)ga,
          (__attribute__((address_space(3))) uint32_t*)&As[buf][c * 8], 16, 0, 0);
    }
#pragma unroll
    for (int ii = 0; ii < 4; ++ii) {  // B: 1024 chunks (128 rows x 8)
      int c = t + 256 * ii;
      int row = c >> 3, sc = c & 7;
      const unsigned short* gb =
          W + (size_t)(n0 + row) * K + k0 + ((sc ^ (row & 7)) << 3);
      __builtin_amdgcn_global_load_lds(
          (const __attribute__((address_space(1))) uint32_t*)gb,
          (__attribute__((address_space(3))) uint32_t*)&Bs[buf][c * 8], 16, 0, 0);
    }
  };

  f32x4 acc[2][4];
#pragma unroll
  for (int mi = 0; mi < 2; ++mi)
#pragma unroll
    for (int ni = 0; ni < 4; ++ni) acc[mi][ni] = (f32x4){0.f, 0.f, 0.f, 0.f};

  STAGE(0, 0);
  __syncthreads();
  int cur = 0;
  for (int k0 = 0; k0 < K; k0 += 64) {
    if (k0 + 64 < K) STAGE(cur ^ 1, k0 + 64);  // prefetch next K-tile
#pragma unroll
    for (int ks = 0; ks < 2; ++ks) {
      s16x8 af[2], bf[4];
#pragma unroll
      for (int mi = 0; mi < 2; ++mi)
        af[mi] = *(const s16x8*)&As[cur][(wm * 32 + mi * 16 + r) * 64 +
                                         (((ks * 4 + g) ^ (r & 7)) << 3)];
#pragma unroll
      for (int ni = 0; ni < 4; ++ni)
        bf[ni] = *(const s16x8*)&Bs[cur][(wn * 64 + ni * 16 + r) * 64 +
                                         (((ks * 4 + g) ^ (r & 7)) << 3)];
#pragma unroll
      for (int mi = 0; mi < 2; ++mi)
#pragma unroll
        for (int ni = 0; ni < 4; ++ni)
          acc[mi][ni] = __builtin_amdgcn_mfma_f32_16x16x32_bf16(
              af[mi], bf[ni], acc[mi][ni], 0, 0, 0);
    }
    __syncthreads();
    cur ^= 1;
  }

#pragma unroll
  for (int ni = 0; ni < 4; ++ni) {
    const int col = n0 + wn * 64 + ni * 16 + r;
    const float bv = bias[col];
#pragma unroll
    for (int mi = 0; mi < 2; ++mi) {
#pragma unroll
      for (int rg = 0; rg < 4; ++rg) {
        const int row = m0 + wm * 32 + mi * 16 + g * 4 + rg;
        float v = acc[mi][ni][rg] + bv;
        if (ACT == 1) v = fmaxf(v, 0.f);
        if (ACT == 2) {
          float u = 0.7978845608028654f * (v + 0.044715f * v * v * v);
          float e = __expf(2.f * u);
          float th = 1.f - 2.f / (e + 1.f);
          v = 0.5f * v * (1.f + th);
        }
        if (SCALEQ && col < 512) v *= QSCALE;
        if (OUTBF)
          ((unsigned short*)Cout)[(size_t)row * N + col] = f2bf(v);
        else
          ((float*)Cout)[(size_t)row * N + col] = v;
      }
    }
  }
}

// ---------------------------------------------------------------------------
// 4) MFMA flash attention, swapped operands, V-transpose fused into staging,
//    T14 async-stage (issue tile nt+1 loads before computing tile nt).
//    Block = (128 q, head, batch), 8 waves x 16 q-rows.
// ---------------------------------------------------------------------------
template <int S>
__global__ __launch_bounds__(512) void attn_mfma(
    const unsigned short* __restrict__ Q, int qstride,
    const unsigned short* __restrict__ K, int kstride,
    const unsigned short* __restrict__ V, int vstride,
    unsigned short* __restrict__ O) {
  constexpr int NT = S / 128;
  __shared__ __align__(16) unsigned short Kl[128 * 40];
  __shared__ __align__(16) unsigned short Vl[32 * 136];
  __shared__ __align__(16) unsigned short Pl[8][16 * 136];
  const int t = threadIdx.x;
  const int w = t >> 6, lane = t & 63;
  const int r = lane & 15, g = lane >> 4;
  const int qt = blockIdx.x, h = blockIdx.y, b = blockIdx.z;
  const int q0 = qt * 128 + w * 16;
  const int kvr = t >> 2, dsg = t & 3;  // staging coords: kv row, 8-elem chunk

  // Q as B-frag: lane (r,g) holds Q[q0+r][h*32 + g*8 ..+7] (pre-scaled)
  s16x8 qa = *(const s16x8*)&Q[((size_t)(b * 1024 + q0 + r)) * qstride + h * 32 + g * 8];

  f32x4 o0 = (f32x4){0.f, 0.f, 0.f, 0.f};
  f32x4 o1 = (f32x4){0.f, 0.f, 0.f, 0.f};
  float m = -1e30f, l = 0.f;

  uint4 kA = {}, vA = {}, kB = {}, vB = {};
  auto GLOAD = [&](int nt, uint4& kr, uint4& vr) {
    const int kv0 = nt * 128;
    kr = *(const uint4*)&K[((size_t)(b * S + kv0 + kvr)) * kstride + h * 32 + dsg * 8];
    vr = *(const uint4*)&V[((size_t)(b * S + kv0 + kvr)) * vstride + h * 32 + dsg * 8];
  };
  GLOAD(0, kA, vA);

  for (int nt = 0; nt < NT; ++nt) {
    __syncthreads();  // all waves done reading Kl/Vl of previous tile
    *(uint4*)&Kl[kvr * 40 + dsg * 8] = kA;  // K row-major [128][40]
    {  // V transposed scatter: Vl[d][kv], d = dsg*8+u
      unsigned short vs[8];
      *(uint4*)vs = vA;
#pragma unroll
      for (int u = 0; u < 8; ++u) Vl[(dsg * 8 + u) * 136 + kvr] = vs[u];
    }
    if (nt + 1 < NT) GLOAD(nt + 1, kB, vB);  // in flight during compute
    __syncthreads();

    // S^T = K·Q^T: s[nb][rg] = S[kv = nb*16+g*4+rg][q = r]
    f32x4 s[8];
#pragma unroll
    for (int nb = 0; nb < 8; ++nb) {
      s16x8 ka = *(const s16x8*)&Kl[(nb * 16 + r) * 40 + g * 8];
      s[nb] = __builtin_amdgcn_mfma_f32_16x16x32_bf16(
          ka, qa, (f32x4){0.f, 0.f, 0.f, 0.f}, 0, 0, 0);
    }

    // online softmax for q-row r (exp2 domain), in-lane + 2 shuffles
    float tm = -1e30f;
#pragma unroll
    for (int nb = 0; nb < 8; ++nb) {
      float a01 = fmaxf(s[nb][0], s[nb][1]);
      float a23 = fmaxf(s[nb][2], s[nb][3]);
      tm = fmaxf(tm, fmaxf(a01, a23));
    }
    tm = fmaxf(tm, __shfl_xor(tm, 16));
    tm = fmaxf(tm, __shfl_xor(tm, 32));
    const float mnew = fmaxf(m, tm);
    const float corr = __builtin_amdgcn_exp2f(m - mnew);
    float ps = 0.f;
#pragma unroll
    for (int nb = 0; nb < 8; ++nb) {
      float p0 = __builtin_amdgcn_exp2f(s[nb][0] - mnew);
      float p1 = __builtin_amdgcn_exp2f(s[nb][1] - mnew);
      float p2 = __builtin_amdgcn_exp2f(s[nb][2] - mnew);
      float p3 = __builtin_amdgcn_exp2f(s[nb][3] - mnew);
      ps += (p0 + p1) + (p2 + p3);
      uint2 pv;
      pv.x = cvtpk_bf16(p0, p1);
      pv.y = cvtpk_bf16(p2, p3);
      *(uint2*)&Pl[w][r * 136 + nb * 16 + g * 4] = pv;  // own q-row, b64
    }
    ps += __shfl_xor(ps, 16);
    ps += __shfl_xor(ps, 32);
    l = l * corr + ps;
    m = mnew;
#pragma unroll
    for (int rg = 0; rg < 4; ++rg) { o0[rg] *= corr; o1[rg] *= corr; }

    // O^T[d][q] += VT[d][kv] · P^T[kv][q]  (Pl wave-private)
#pragma unroll
    for (int ks = 0; ks < 4; ++ks) {
      s16x8 va0 = *(const s16x8*)&Vl[r * 136 + ks * 32 + g * 8];
      s16x8 va1 = *(const s16x8*)&Vl[(16 + r) * 136 + ks * 32 + g * 8];
      s16x8 pb  = *(const s16x8*)&Pl[w][r * 136 + ks * 32 + g * 8];
      o0 = __builtin_amdgcn_mfma_f32_16x16x32_bf16(va0, pb, o0, 0, 0, 0);
      o1 = __builtin_amdgcn_mfma_f32_16x16x32_bf16(va1, pb, o1, 0, 0, 0);
    }
    kA = kB; vA = vB;
  }

  // lane (r,g): O[q = q0+r][d = g*4+rg (+16)] ; pack 4 consecutive d -> b64
  const float inv = 1.f / l;
  const size_t row = (size_t)(b * 1024 + q0 + r);
  uint2 w0, w1;
  w0.x = cvtpk_bf16(o0[0] * inv, o0[1] * inv);
  w0.y = cvtpk_bf16(o0[2] * inv, o0[3] * inv);
  w1.x = cvtpk_bf16(o1[0] * inv, o1[1] * inv);
  w1.y = cvtpk_bf16(o1[2] * inv, o1[3] * inv);
  *(uint2*)&O[row * 512 + h * 32 + g * 4]      = w0;
  *(uint2*)&O[row * 512 + h * 32 + 16 + g * 4] = w1;
}

// ---------------------------------------------------------------------------
// 5) LayerNorm(X + A) * g + b -> bf16 [row][512].  XBF/ABF: inputs bf16.
// ---------------------------------------------------------------------------
template <int XBF, int ABF>
__global__ __launch_bounds__(256) void ln_kernel(
    const void* __restrict__ X, const void* __restrict__ A,
    const float* __restrict__ gw, const float* __restrict__ bw,
    unsigned short* __restrict__ O) {
  const int rr = blockIdx.x;
  const int t = threadIdx.x;
  const size_t base = (size_t)rr * 512;
  float x0, x1, a0, a1;
  if (XBF) {
    x0 = bf2f(((const unsigned short*)X)[base + t]);
    x1 = bf2f(((const unsigned short*)X)[base + t + 256]);
  } else {
    x0 = ((const float*)X)[base + t];
    x1 = ((const float*)X)[base + t + 256];
  }
  if (ABF) {
    a0 = bf2f(((const unsigned short*)A)[base + t]);
    a1 = bf2f(((const unsigned short*)A)[base + t + 256]);
  } else {
    a0 = ((const float*)A)[base + t];
    a1 = ((const float*)A)[base + t + 256];
  }
  float v0 = x0 + a0;
  float v1 = x1 + a1;
  __shared__ float wsum[4];
  float s = v0 + v1;
#pragma unroll
  for (int of = 32; of; of >>= 1) s += __shfl_down(s, of);
  if ((t & 63) == 0) wsum[t >> 6] = s;
  __syncthreads();
  const float mean = (wsum[0] + wsum[1] + wsum[2] + wsum[3]) * (1.f / 512.f);
  __syncthreads();
  float d0 = v0 - mean, d1 = v1 - mean;
  float s2 = d0 * d0 + d1 * d1;
#pragma unroll
  for (int of = 32; of; of >>= 1) s2 += __shfl_down(s2, of);
  if ((t & 63) == 0) wsum[t >> 6] = s2;
  __syncthreads();
  const float var = (wsum[0] + wsum[1] + wsum[2] + wsum[3]) * (1.f / 512.f);
  const float rstd = rsqrtf(var + 1e-5f);
  O[base + t] = f2bf(d0 * rstd * gw[t] + bw[t]);
  O[base + t + 256] = f2bf(d1 * rstd * gw[t + 256] + bw[t + 256]);
}

// ---------------------------------------------------------------------------
// 6) final transpose: h3 bf16 [b*1024+l][512] -> out f32 [b][c][l], 64x64 tiles
// ---------------------------------------------------------------------------
__global__ __launch_bounds__(256) void transpose_out_kernel(
    const unsigned short* __restrict__ h3, float* __restrict__ out) {
  __shared__ float tile[64][65];
  const int t = threadIdx.x;
  const int lt = blockIdx.x * 64, ct = blockIdx.y * 64, b = blockIdx.z;
#pragma unroll
  for (int ii = 0; ii < 2; ++ii) {
    int idx = t + 256 * ii;          // 512 chunks = 64 rows x 8
    int row = idx >> 3, ch = idx & 7;
    uint4 v = *(const uint4*)&h3[((size_t)(b * 1024 + lt + row)) * 512 + ct + ch * 8];
    unsigned short vs[8];
    *(uint4*)vs = v;
#pragma unroll
    for (int u = 0; u < 8; ++u) tile[row][ch * 8 + u] = bf2f(vs[u]);
  }
  __syncthreads();
  const int c = t >> 2, l0 = (t & 3) * 16;
  float* op = &out[((size_t)(b * 512 + ct + c)) * 1024 + lt + l0];
#pragma unroll
  for (int i = 0; i < 4; ++i) {
    float4 o4 = {tile[l0 + i * 4 + 0][c], tile[l0 + i * 4 + 1][c],
                 tile[l0 + i * 4 + 2][c], tile[l0 + i * 4 + 3][c]};
    *(float4*)(op + i * 4) = o4;
  }
}

// ---------------------------------------------------------------------------
extern "C" void kernel_launch(void* const* d_in, const int* in_sizes, int n_in,
                              void* d_out, int out_size, void* d_ws, size_t ws_size,
                              hipStream_t stream) {
  const float* x      = (const float*)d_in[0];
  const float* gf     = (const float*)d_in[1];
  const float* conv_w = (const float*)d_in[2];
  const float* conv_b = (const float*)d_in[3];
  const float* sWq = (const float*)d_in[4],  *sbq = (const float*)d_in[5];
  const float* sWk = (const float*)d_in[6],  *sbk = (const float*)d_in[7];
  const float* sWv = (const float*)d_in[8],  *sbv = (const float*)d_in[9];
  const float* sWo = (const float*)d_in[10], *sbo = (const float*)d_in[11];
  const float* cWq = (const float*)d_in[12], *cbq = (const float*)d_in[13];
  const float* cWk = (const float*)d_in[14], *cbk = (const float*)d_in[15];
  const float* cWv = (const float*)d_in[16], *cbv = (const float*)d_in[17];
  const float* cWo = (const float*)d_in[18], *cbo = (const float*)d_in[19];
  const float* fw1 = (const float*)d_in[20], *fb1 = (const float*)d_in[21];
  const float* fw2 = (const float*)d_in[22], *fb2 = (const float*)d_in[23];
  const float* ln1_g = (const float*)d_in[24], *ln1_b = (const float*)d_in[25];
  const float* ln2_g = (const float*)d_in[26], *ln2_b = (const float*)d_in[27];
  const float* ln3_g = (const float*)d_in[28], *ln3_b = (const float*)d_in[29];
  float* out = (float*)d_out;

  // bf16 conversion pool (ushort element offsets):
  unsigned short* bfp = (unsigned short*)d_ws;
  unsigned short* conv_wb = bfp + 0;
  unsigned short* sWqb = bfp + 262144;   // [Wq;Wk;Wv] contiguous = fused QKV W
  unsigned short* cWqb = bfp + 1310720;
  unsigned short* cWkb = bfp + 1572864;  // [cWk;cWv] contiguous = fused cKV W
  unsigned short* cWob = bfp + 2097152;
  unsigned short* sWob = bfp + 1048576;
  unsigned short* fw1b = bfp + 2359296, *fw2b = bfp + 3407872;
  unsigned short* xbf  = bfp + 4456448;  // pool ends at el 6,553,600

  unsigned short* SC   = bfp + 6553600;
  unsigned short* qkvb = SC;                  // 6,291,456  [4096][1536]
  unsigned short* ckvb = SC + 6291456;        // 2,097,152  [2048][1024]
  unsigned short* qcb  = SC + 8388608;        // 2,097,152  (statTb overlays)
  unsigned short* ctxb = SC + 12582912;       // 2,097,152  (crossb overlays)
  unsigned short* projb= SC + 14680064;       // 2,097,152  (biasf overlays head)
  unsigned short* hbf  = SC + 16777216;       // 2,097,152  (h3 reuses)
  unsigned short* h2bf = SC + 18874368;       // 2,097,152  (SC ends 20,971,520)
  unsigned short* statTb = qcb;
  unsigned short* crossb = ctxb;
  unsigned short* midb   = qkvb;              // 8,388,608 = qkvb+ckvb (dead then)
  float* biasf = (float*)projb;               // [1536 qkv | 1024 ckv] f32

  prep_kernel<<<7297, 256, 0, stream>>>(
      conv_w, sWq, sWk, sWv, sWo, cWq, cWk, cWv, cWo, fw1, fw2, x, bfp,
      gf, statTb, sbq, sbk, sbv, cbk, cbv, biasf);

  // pointwise conv + relu -> cross tokens [2048][512]
  gemm_bf16<1, 1, 0><<<dim3(4, 32), 256, 0, stream>>>(
      statTb, conv_wb, conv_b, crossb, 2048, 512, 512);
  // fused self QKV [4096][1536], Q cols pre-scaled
  gemm_bf16<0, 1, 1><<<dim3(12, 64), 256, 0, stream>>>(
      xbf, sWqb, biasf, qkvb, 4096, 1536, 512);
  // fused cross KV [2048][1024]
  gemm_bf16<0, 1, 0><<<dim3(8, 32), 256, 0, stream>>>(
      crossb, cWkb, biasf + 1536, ckvb, 2048, 1024, 512);

  // self-attention (V transpose fused in staging)
  attn_mfma<1024><<<dim3(8, 16, 4), 512, 0, stream>>>(
      qkvb, 1536, qkvb + 512, 1536, qkvb + 1024, 1536, ctxb);
  gemm_bf16<0, 1, 0><<<dim3(4, 64), 256, 0, stream>>>(
      ctxb, sWob, sbo, projb, 4096, 512, 512);
  ln_kernel<0, 1><<<4096, 256, 0, stream>>>(x, projb, ln1_g, ln1_b, hbf);

  // cross-attention (K/V from conv tokens, S=512)
  gemm_bf16<0, 1, 1><<<dim3(4, 64), 256, 0, stream>>>(
      hbf, cWqb, cbq, qcb, 4096, 512, 512);
  attn_mfma<512><<<dim3(8, 16, 4), 512, 0, stream>>>(
      qcb, 512, ckvb, 1024, ckvb + 512, 1024, ctxb);
  gemm_bf16<0, 1, 0><<<dim3(4, 64), 256, 0, stream>>>(
      ctxb, cWob, cbo, projb, 4096, 512, 512);
  ln_kernel<1, 1><<<4096, 256, 0, stream>>>(hbf, projb, ln2_g, ln2_b, h2bf);

  // FFN + final LN (bf16) + tiled f32 transpose to [b][c][l]
  gemm_bf16<2, 1, 0><<<dim3(16, 64), 256, 0, stream>>>(
      h2bf, fw1b, fb1, midb, 4096, 2048, 512);
  gemm_bf16<0, 1, 0><<<dim3(4, 64), 256, 0, stream>>>(
      midb, fw2b, fb2, projb, 4096, 512, 2048);
  ln_kernel<1, 1><<<4096, 256, 0, stream>>>(h2bf, projb, ln3_g, ln3_b, hbf);
  transpose_out_kernel<<<dim3(16, 8, 4), 256, 0, stream>>>(hbf, out);
}

// Round 7
// 335.536 us; speedup vs baseline: 7.8510x; 1.0488x over previous
//
#include <hip/hip_runtime.h>
#include <stdint.h>
#include <math.h>

// B=4, L1=1024, D=512, H=16, DH=32, L=8192, win=16, NW=512, DFF=2048

typedef short  s16x8 __attribute__((ext_vector_type(8)));
typedef float  f32x4 __attribute__((ext_vector_type(4)));

__device__ inline unsigned short f2bf(float f) {
  uint32_t u = __builtin_bit_cast(uint32_t, f);
  u += 0x7fffu + ((u >> 16) & 1u);
  return (unsigned short)(u >> 16);
}
__device__ inline float bf2f(unsigned short h) {
  uint32_t u = ((uint32_t)h) << 16;
  return __builtin_bit_cast(float, u);
}
// pack 2 f32 -> 2 bf16 in one VALU op (src0 -> low half)
__device__ inline uint32_t cvtpk_bf16(float lo, float hi) {
  uint32_t r;
  asm("v_cvt_pk_bf16_f32 %0, %1, %2" : "=v"(r) : "v"(lo), "v"(hi));
  return r;
}

// scale(1/sqrt(32)) * log2(e): folded into Q so softmax is pure exp2
#define QSCALE 0.25503486611627154f

// ---------------------------------------------------------------------------
// 0) prep: f32->bf16 weight/x pool  |  window stat (transposed)  |  bias cat
//    grid: [0,3200) convert, [3200,7296) window stat, 7296 biascat
//    window-stat lanes map n fastest -> wave reads 4KB contiguous from gf.
// ---------------------------------------------------------------------------
__global__ __launch_bounds__(256) void prep_kernel(
    const float* s0, const float* s1, const float* s2, const float* s3,
    const float* s4, const float* s5, const float* s6, const float* s7,
    const float* s8, const float* s9, const float* s10, const float* s11,
    unsigned short* dst,
    const float* __restrict__ gf, unsigned short* __restrict__ statT,
    const float* __restrict__ sbq, const float* __restrict__ sbk,
    const float* __restrict__ sbv, const float* __restrict__ cbk,
    const float* __restrict__ cbv, float* __restrict__ biasf) {
  const int bid = blockIdx.x;
  const int t = threadIdx.x;
  if (bid < 3200) {
    const size_t cum[13] = {0, 262144, 524288, 786432, 1048576, 1310720,
                            1572864, 1835008, 2097152, 2359296, 3407872,
                            4456448, 6553600};
    const float* srcs[12] = {s0, s1, s2, s3, s4, s5, s6, s7, s8, s9, s10, s11};
    size_t e0 = ((size_t)bid * 256 + t) * 8;
    int seg = 0;
    while (e0 >= cum[seg + 1]) ++seg;
    const float* sp = srcs[seg] + (e0 - cum[seg]);
    float4 a = *(const float4*)sp;
    float4 b = *(const float4*)(sp + 4);
    unsigned short o[8] = {f2bf(a.x), f2bf(a.y), f2bf(a.z), f2bf(a.w),
                           f2bf(b.x), f2bf(b.y), f2bf(b.z), f2bf(b.w)};
    *(uint4*)&dst[e0] = *(const uint4*)o;
  } else if (bid < 7296) {
    int gidx = (bid - 3200) * 256 + t;
    int n = gidx & 511;             // fastest: consecutive lanes -> coalesced
    int c = (gidx >> 9) & 511;
    int b = gidx >> 18;
    const float4* p = (const float4*)(gf + ((size_t)(b * 512 + c) << 13) + n * 16);
    float4 w0 = p[0], w1 = p[1], w2 = p[2], w3 = p[3];
    float mx = w0.x, mn = w0.x;
    float vals[15] = {w0.y, w0.z, w0.w, w1.x, w1.y, w1.z, w1.w,
                      w2.x, w2.y, w2.z, w2.w, w3.x, w3.y, w3.z, w3.w};
#pragma unroll
    for (int i = 0; i < 15; ++i) {
      mx = fmaxf(mx, vals[i]);
      mn = fminf(mn, vals[i]);
    }
    statT[((size_t)(b * 512 + n) << 9) + c] = f2bf(mx - mn);
  } else {
    for (int i = t; i < 2560; i += 256) {
      float v;
      if (i < 512) v = sbq[i];
      else if (i < 1024) v = sbk[i - 512];
      else if (i < 1536) v = sbv[i - 1024];
      else if (i < 2048) v = cbk[i - 1536];
      else v = cbv[i - 2048];
      biasf[i] = v;
    }
  }
}

// ---------------------------------------------------------------------------
// 2) bf16 MFMA GEMM, BK=64, 2-phase dbuf, T2 XOR swizzle (rule-21 pattern).
//    BM=64, BN template (64 or 128), 4 waves (2x2), per-wave 32x(BN/2).
//    BN=64 doubles block count for N<=1024 problems -> 2 blocks/CU.
// ---------------------------------------------------------------------------
template <int ACT, int OUTBF, int SCALEQ, int BN>
__global__ __launch_bounds__(256) void gemm_bf16(
    const unsigned short* __restrict__ A, const unsigned short* __restrict__ W,
    const float* __restrict__ bias, void* __restrict__ Cout,
    int M, int N, int K) {
  constexpr int NFR = BN / 32;  // 16-wide frags per wave in N
  __shared__ __align__(16) unsigned short As[2][64 * 64];
  __shared__ __align__(16) unsigned short Bs[2][BN * 64];
  const int t = threadIdx.x;
  const int w = t >> 6, lane = t & 63;
  const int r = lane & 15, g = lane >> 4;
  const int wm = w >> 1, wn = w & 1;
  const int m0 = blockIdx.y * 64, n0 = blockIdx.x * BN;

  auto STAGE = [&](int buf, int k0) {
#pragma unroll
    for (int ii = 0; ii < 2; ++ii) {  // A: 512 16B chunks (64 rows x 8)
      int c = t + 256 * ii;
      int row = c >> 3, sc = c & 7;
      const unsigned short* ga =
          A + (size_t)(m0 + row) * K + k0 + ((sc ^ (row & 7)) << 3);
      __builtin_amdgcn_global_load_lds(
          (const __attribute__((address_space(1))) uint32_t*)ga,
          (__attribute__((address_space(3))) uint32_t*)&As[buf][c * 8], 16, 0, 0);
    }
#pragma unroll
    for (int ii = 0; ii < BN / 32; ++ii) {  // B: BN*8 chunks
      int c = t + 256 * ii;
      int row = c >> 3, sc = c & 7;
      const unsigned short* gb =
          W + (size_t)(n0 + row) * K + k0 + ((sc ^ (row & 7)) << 3);
      __builtin_amdgcn_global_load_lds(
          (const __attribute__((address_space(1))) uint32_t*)gb,
          (__attribute__((address_space(3))) uint32_t*)&Bs[buf][c * 8], 16, 0, 0);
    }
  };

  f32x4 acc[2][NFR];
#pragma unroll
  for (int mi = 0; mi < 2; ++mi)
#pragma unroll
    for (int ni = 0; ni < NFR; ++ni) acc[mi][ni] = (f32x4){0.f, 0.f, 0.f, 0.f};

  STAGE(0, 0);
  __syncthreads();
  int cur = 0;
  for (int k0 = 0; k0 < K; k0 += 64) {
    if (k0 + 64 < K) STAGE(cur ^ 1, k0 + 64);  // prefetch next K-tile
#pragma unroll
    for (int ks = 0; ks < 2; ++ks) {
      s16x8 af[2], bf[NFR];
#pragma unroll
      for (int mi = 0; mi < 2; ++mi)
        af[mi] = *(const s16x8*)&As[cur][(wm * 32 + mi * 16 + r) * 64 +
                                         (((ks * 4 + g) ^ (r & 7)) << 3)];
#pragma unroll
      for (int ni = 0; ni < NFR; ++ni)
        bf[ni] = *(const s16x8*)&Bs[cur][(wn * (BN / 2) + ni * 16 + r) * 64 +
                                         (((ks * 4 + g) ^ (r & 7)) << 3)];
#pragma unroll
      for (int mi = 0; mi < 2; ++mi)
#pragma unroll
        for (int ni = 0; ni < NFR; ++ni)
          acc[mi][ni] = __builtin_amdgcn_mfma_f32_16x16x32_bf16(
              af[mi], bf[ni], acc[mi][ni], 0, 0, 0);
    }
    __syncthreads();
    cur ^= 1;
  }

#pragma unroll
  for (int ni = 0; ni < NFR; ++ni) {
    const int col = n0 + wn * (BN / 2) + ni * 16 + r;
    const float bv = bias[col];
#pragma unroll
    for (int mi = 0; mi < 2; ++mi) {
#pragma unroll
      for (int rg = 0; rg < 4; ++rg) {
        const int row = m0 + wm * 32 + mi * 16 + g * 4 + rg;
        float v = acc[mi][ni][rg] + bv;
        if (ACT == 1) v = fmaxf(v, 0.f);
        if (ACT == 2) {
          float u = 0.7978845608028654f * (v + 0.044715f * v * v * v);
          float e = __expf(2.f * u);
          float th = 1.f - 2.f / (e + 1.f);
          v = 0.5f * v * (1.f + th);
        }
        if (SCALEQ && col < 512) v *= QSCALE;
        if (OUTBF)
          ((unsigned short*)Cout)[(size_t)row * N + col] = f2bf(v);
        else
          ((float*)Cout)[(size_t)row * N + col] = v;
      }
    }
  }
}

// ---------------------------------------------------------------------------
// 4) MFMA flash attention, swapped operands, V-transpose fused into staging,
//    T14 async-stage, T5 setprio around MFMA clusters.
//    Block = (128 q, head, batch), 8 waves x 16 q-rows.
// ---------------------------------------------------------------------------
template <int S>
__global__ __launch_bounds__(512) void attn_mfma(
    const unsigned short* __restrict__ Q, int qstride,
    const unsigned short* __restrict__ K, int kstride,
    const unsigned short* __restrict__ V, int vstride,
    unsigned short* __restrict__ O) {
  constexpr int NT = S / 128;
  __shared__ __align__(16) unsigned short Kl[128 * 40];
  __shared__ __align__(16) unsigned short Vl[32 * 136];
  __shared__ __align__(16) unsigned short Pl[8][16 * 136];
  const int t = threadIdx.x;
  const int w = t >> 6, lane = t & 63;
  const int r = lane & 15, g = lane >> 4;
  const int qt = blockIdx.x, h = blockIdx.y, b = blockIdx.z;
  const int q0 = qt * 128 + w * 16;
  const int kvr = t >> 2, dsg = t & 3;  // staging coords: kv row, 8-elem chunk

  // Q as B-frag: lane (r,g) holds Q[q0+r][h*32 + g*8 ..+7] (pre-scaled)
  s16x8 qa = *(const s16x8*)&Q[((size_t)(b * 1024 + q0 + r)) * qstride + h * 32 + g * 8];

  f32x4 o0 = (f32x4){0.f, 0.f, 0.f, 0.f};
  f32x4 o1 = (f32x4){0.f, 0.f, 0.f, 0.f};
  float m = -1e30f, l = 0.f;

  uint4 kA = {}, vA = {}, kB = {}, vB = {};
  auto GLOAD = [&](int nt, uint4& kr, uint4& vr) {
    const int kv0 = nt * 128;
    kr = *(const uint4*)&K[((size_t)(b * S + kv0 + kvr)) * kstride + h * 32 + dsg * 8];
    vr = *(const uint4*)&V[((size_t)(b * S + kv0 + kvr)) * vstride + h * 32 + dsg * 8];
  };
  GLOAD(0, kA, vA);

  for (int nt = 0; nt < NT; ++nt) {
    __syncthreads();  // all waves done reading Kl/Vl of previous tile
    *(uint4*)&Kl[kvr * 40 + dsg * 8] = kA;  // K row-major [128][40]
    {  // V transposed scatter: Vl[d][kv], d = dsg*8+u
      unsigned short vs[8];
      *(uint4*)vs = vA;
#pragma unroll
      for (int u = 0; u < 8; ++u) Vl[(dsg * 8 + u) * 136 + kvr] = vs[u];
    }
    if (nt + 1 < NT) GLOAD(nt + 1, kB, vB);  // in flight during compute
    __syncthreads();

    // S^T = K·Q^T: s[nb][rg] = S[kv = nb*16+g*4+rg][q = r]
    f32x4 s[8];
    __builtin_amdgcn_s_setprio(1);
#pragma unroll
    for (int nb = 0; nb < 8; ++nb) {
      s16x8 ka = *(const s16x8*)&Kl[(nb * 16 + r) * 40 + g * 8];
      s[nb] = __builtin_amdgcn_mfma_f32_16x16x32_bf16(
          ka, qa, (f32x4){0.f, 0.f, 0.f, 0.f}, 0, 0, 0);
    }
    __builtin_amdgcn_s_setprio(0);

    // online softmax for q-row r (exp2 domain), in-lane + 2 shuffles
    float tm = -1e30f;
#pragma unroll
    for (int nb = 0; nb < 8; ++nb) {
      float a01 = fmaxf(s[nb][0], s[nb][1]);
      float a23 = fmaxf(s[nb][2], s[nb][3]);
      tm = fmaxf(tm, fmaxf(a01, a23));
    }
    tm = fmaxf(tm, __shfl_xor(tm, 16));
    tm = fmaxf(tm, __shfl_xor(tm, 32));
    const float mnew = fmaxf(m, tm);
    const float corr = __builtin_amdgcn_exp2f(m - mnew);
    float ps = 0.f;
#pragma unroll
    for (int nb = 0; nb < 8; ++nb) {
      float p0 = __builtin_amdgcn_exp2f(s[nb][0] - mnew);
      float p1 = __builtin_amdgcn_exp2f(s[nb][1] - mnew);
      float p2 = __builtin_amdgcn_exp2f(s[nb][2] - mnew);
      float p3 = __builtin_amdgcn_exp2f(s[nb][3] - mnew);
      ps += (p0 + p1) + (p2 + p3);
      uint2 pv;
      pv.x = cvtpk_bf16(p0, p1);
      pv.y = cvtpk_bf16(p2, p3);
      *(uint2*)&Pl[w][r * 136 + nb * 16 + g * 4] = pv;  // own q-row, b64
    }
    ps += __shfl_xor(ps, 16);
    ps += __shfl_xor(ps, 32);
    l = l * corr + ps;
    m = mnew;
#pragma unroll
    for (int rg = 0; rg < 4; ++rg) { o0[rg] *= corr; o1[rg] *= corr; }

    // O^T[d][q] += VT[d][kv] · P^T[kv][q]  (Pl wave-private)
    __builtin_amdgcn_s_setprio(1);
#pragma unroll
    for (int ks = 0; ks < 4; ++ks) {
      s16x8 va0 = *(const s16x8*)&Vl[r * 136 + ks * 32 + g * 8];
      s16x8 va1 = *(const s16x8*)&Vl[(16 + r) * 136 + ks * 32 + g * 8];
      s16x8 pb  = *(const s16x8*)&Pl[w][r * 136 + ks * 32 + g * 8];
      o0 = __builtin_amdgcn_mfma_f32_16x16x32_bf16(va0, pb, o0, 0, 0, 0);
      o1 = __builtin_amdgcn_mfma_f32_16x16x32_bf16(va1, pb, o1, 0, 0, 0);
    }
    __builtin_amdgcn_s_setprio(0);
    kA = kB; vA = vB;
  }

  // lane (r,g): O[q = q0+r][d = g*4+rg (+16)] ; pack 4 consecutive d -> b64
  const float inv = 1.f / l;
  const size_t row = (size_t)(b * 1024 + q0 + r);
  uint2 w0, w1;
  w0.x = cvtpk_bf16(o0[0] * inv, o0[1] * inv);
  w0.y = cvtpk_bf16(o0[2] * inv, o0[3] * inv);
  w1.x = cvtpk_bf16(o1[0] * inv, o1[1] * inv);
  w1.y = cvtpk_bf16(o1[2] * inv, o1[3] * inv);
  *(uint2*)&O[row * 512 + h * 32 + g * 4]      = w0;
  *(uint2*)&O[row * 512 + h * 32 + 16 + g * 4] = w1;
}

// ---------------------------------------------------------------------------
// 5) LayerNorm(X + A) * g + b -> bf16 [row][512].  XBF/ABF: inputs bf16.
// ---------------------------------------------------------------------------
template <int XBF, int ABF>
__global__ __launch_bounds__(256) void ln_kernel(
    const void* __restrict__ X, const void* __restrict__ A,
    const float* __restrict__ gw, const float* __restrict__ bw,
    unsigned short* __restrict__ O) {
  const int rr = blockIdx.x;
  const int t = threadIdx.x;
  const size_t base = (size_t)rr * 512;
  float x0, x1, a0, a1;
  if (XBF) {
    x0 = bf2f(((const unsigned short*)X)[base + t]);
    x1 = bf2f(((const unsigned short*)X)[base + t + 256]);
  } else {
    x0 = ((const float*)X)[base + t];
    x1 = ((const float*)X)[base + t + 256];
  }
  if (ABF) {
    a0 = bf2f(((const unsigned short*)A)[base + t]);
    a1 = bf2f(((const unsigned short*)A)[base + t + 256]);
  } else {
    a0 = ((const float*)A)[base + t];
    a1 = ((const float*)A)[base + t + 256];
  }
  float v0 = x0 + a0;
  float v1 = x1 + a1;
  __shared__ float wsum[4];
  float s = v0 + v1;
#pragma unroll
  for (int of = 32; of; of >>= 1) s += __shfl_down(s, of);
  if ((t & 63) == 0) wsum[t >> 6] = s;
  __syncthreads();
  const float mean = (wsum[0] + wsum[1] + wsum[2] + wsum[3]) * (1.f / 512.f);
  __syncthreads();
  float d0 = v0 - mean, d1 = v1 - mean;
  float s2 = d0 * d0 + d1 * d1;
#pragma unroll
  for (int of = 32; of; of >>= 1) s2 += __shfl_down(s2, of);
  if ((t & 63) == 0) wsum[t >> 6] = s2;
  __syncthreads();
  const float var = (wsum[0] + wsum[1] + wsum[2] + wsum[3]) * (1.f / 512.f);
  const float rstd = rsqrtf(var + 1e-5f);
  O[base + t] = f2bf(d0 * rstd * gw[t] + bw[t]);
  O[base + t + 256] = f2bf(d1 * rstd * gw[t + 256] + bw[t + 256]);
}

// ---------------------------------------------------------------------------
// 6) final transpose: h3 bf16 [b*1024+l][512] -> out f32 [b][c][l], 64x64 tiles
// ---------------------------------------------------------------------------
__global__ __launch_bounds__(256) void transpose_out_kernel(
    const unsigned short* __restrict__ h3, float* __restrict__ out) {
  __shared__ float tile[64][65];
  const int t = threadIdx.x;
  const int lt = blockIdx.x * 64, ct = blockIdx.y * 64, b = blockIdx.z;
#pragma unroll
  for (int ii = 0; ii < 2; ++ii) {
    int idx = t + 256 * ii;          // 512 chunks = 64 rows x 8
    int row = idx >> 3, ch = idx & 7;
    uint4 v = *(const uint4*)&h3[((size_t)(b * 1024 + lt + row)) * 512 + ct + ch * 8];
    unsigned short vs[8];
    *(uint4*)vs = v;
#pragma unroll
    for (int u = 0; u < 8; ++u) tile[row][ch * 8 + u] = bf2f(vs[u]);
  }
  __syncthreads();
  const int c = t >> 2, l0 = (t & 3) * 16;
  float* op = &out[((size_t)(b * 512 + ct + c)) * 1024 + lt + l0];
#pragma unroll
  for (int i = 0; i < 4; ++i) {
    float4 o4 = {tile[l0 + i * 4 + 0][c], tile[l0 + i * 4 + 1][c],
                 tile[l0 + i * 4 + 2][c], tile[l0 + i * 4 + 3][c]};
    *(float4*)(op + i * 4) = o4;
  }
}

// ---------------------------------------------------------------------------
extern "C" void kernel_launch(void* const* d_in, const int* in_sizes, int n_in,
                              void* d_out, int out_size, void* d_ws, size_t ws_size,
                              hipStream_t stream) {
  const float* x      = (const float*)d_in[0];
  const float* gf     = (const float*)d_in[1];
  const float* conv_w = (const float*)d_in[2];
  const float* conv_b = (const float*)d_in[3];
  const float* sWq = (const float*)d_in[4],  *sbq = (const float*)d_in[5];
  const float* sWk = (const float*)d_in[6],  *sbk = (const float*)d_in[7];
  const float* sWv = (const float*)d_in[8],  *sbv = (const float*)d_in[9];
  const float* sWo = (const float*)d_in[10], *sbo = (const float*)d_in[11];
  const float* cWq = (const float*)d_in[12], *cbq = (const float*)d_in[13];
  const float* cWk = (const float*)d_in[14], *cbk = (const float*)d_in[15];
  const float* cWv = (const float*)d_in[16], *cbv = (const float*)d_in[17];
  const float* cWo = (const float*)d_in[18], *cbo = (const float*)d_in[19];
  const float* fw1 = (const float*)d_in[20], *fb1 = (const float*)d_in[21];
  const float* fw2 = (const float*)d_in[22], *fb2 = (const float*)d_in[23];
  const float* ln1_g = (const float*)d_in[24], *ln1_b = (const float*)d_in[25];
  const float* ln2_g = (const float*)d_in[26], *ln2_b = (const float*)d_in[27];
  const float* ln3_g = (const float*)d_in[28], *ln3_b = (const float*)d_in[29];
  float* out = (float*)d_out;

  // bf16 conversion pool (ushort element offsets):
  unsigned short* bfp = (unsigned short*)d_ws;
  unsigned short* conv_wb = bfp + 0;
  unsigned short* sWqb = bfp + 262144;   // [Wq;Wk;Wv] contiguous = fused QKV W
  unsigned short* cWqb = bfp + 1310720;
  unsigned short* cWkb = bfp + 1572864;  // [cWk;cWv] contiguous = fused cKV W
  unsigned short* cWob = bfp + 2097152;
  unsigned short* sWob = bfp + 1048576;
  unsigned short* fw1b = bfp + 2359296, *fw2b = bfp + 3407872;
  unsigned short* xbf  = bfp + 4456448;  // pool ends at el 6,553,600

  unsigned short* SC   = bfp + 6553600;
  unsigned short* qkvb = SC;                  // 6,291,456  [4096][1536]
  unsigned short* ckvb = SC + 6291456;        // 2,097,152  [2048][1024]
  unsigned short* qcb  = SC + 8388608;        // 2,097,152  (statTb overlays)
  unsigned short* ctxb = SC + 12582912;       // 2,097,152  (crossb overlays)
  unsigned short* projb= SC + 14680064;       // 2,097,152  (biasf overlays head)
  unsigned short* hbf  = SC + 16777216;       // 2,097,152  (h3 reuses)
  unsigned short* h2bf = SC + 18874368;       // 2,097,152  (SC ends 20,971,520)
  unsigned short* statTb = qcb;
  unsigned short* crossb = ctxb;
  unsigned short* midb   = qkvb;              // 8,388,608 = qkvb+ckvb (dead then)
  float* biasf = (float*)projb;               // [1536 qkv | 1024 ckv] f32

  prep_kernel<<<7297, 256, 0, stream>>>(
      conv_w, sWq, sWk, sWv, sWo, cWq, cWk, cWv, cWo, fw1, fw2, x, bfp,
      gf, statTb, sbq, sbk, sbv, cbk, cbv, biasf);

  // pointwise conv + relu -> cross tokens [2048][512]
  gemm_bf16<1, 1, 0, 64><<<dim3(8, 32), 256, 0, stream>>>(
      statTb, conv_wb, conv_b, crossb, 2048, 512, 512);
  // fused self QKV [4096][1536], Q cols pre-scaled
  gemm_bf16<0, 1, 1, 128><<<dim3(12, 64), 256, 0, stream>>>(
      xbf, sWqb, biasf, qkvb, 4096, 1536, 512);
  // fused cross KV [2048][1024]
  gemm_bf16<0, 1, 0, 64><<<dim3(16, 32), 256, 0, stream>>>(
      crossb, cWkb, biasf + 1536, ckvb, 2048, 1024, 512);

  // self-attention (V transpose fused in staging)
  attn_mfma<1024><<<dim3(8, 16, 4), 512, 0, stream>>>(
      qkvb, 1536, qkvb + 512, 1536, qkvb + 1024, 1536, ctxb);
  gemm_bf16<0, 1, 0, 64><<<dim3(8, 64), 256, 0, stream>>>(
      ctxb, sWob, sbo, projb, 4096, 512, 512);
  ln_kernel<0, 1><<<4096, 256, 0, stream>>>(x, projb, ln1_g, ln1_b, hbf);

  // cross-attention (K/V from conv tokens, S=512)
  gemm_bf16<0, 1, 1, 64><<<dim3(8, 64), 256, 0, stream>>>(
      hbf, cWqb, cbq, qcb, 4096, 512, 512);
  attn_mfma<512><<<dim3(8, 16, 4), 512, 0, stream>>>(
      qcb, 512, ckvb, 1024, ckvb + 512, 1024, ctxb);
  gemm_bf16<0, 1, 0, 64><<<dim3(8, 64), 256, 0, stream>>>(
      ctxb, cWob, cbo, projb, 4096, 512, 512);
  ln_kernel<1, 1><<<4096, 256, 0, stream>>>(hbf, projb, ln2_g, ln2_b, h2bf);

  // FFN + final LN (bf16) + tiled f32 transpose to [b][c][l]
  gemm_bf16<2, 1, 0, 128><<<dim3(16, 64), 256, 0, stream>>>(
      h2bf, fw1b, fb1, midb, 4096, 2048, 512);
  gemm_bf16<0, 1, 0, 64><<<dim3(8, 64), 256, 0, stream>>>(
      midb, fw2b, fb2, projb, 4096, 512, 2048);
  ln_kernel<1, 1><<<4096, 256, 0, stream>>>(h2bf, projb, ln3_g, ln3_b, hbf);
  transpose_out_kernel<<<dim3(16, 8, 4), 256, 0, stream>>>(hbf, out);
}

// Round 8
// 330.879 us; speedup vs baseline: 7.9615x; 1.0141x over previous
//
#include <hip/hip_runtime.h>
#include <stdint.h>
#include <math.h>

// B=4, L1=1024, D=512, H=16, DH=32, L=8192, win=16, NW=512, DFF=2048

typedef short  s16x8 __attribute__((ext_vector_type(8)));
typedef float  f32x4 __attribute__((ext_vector_type(4)));

__device__ inline unsigned short f2bf(float f) {
  uint32_t u = __builtin_bit_cast(uint32_t, f);
  u += 0x7fffu + ((u >> 16) & 1u);
  return (unsigned short)(u >> 16);
}
__device__ inline float bf2f(unsigned short h) {
  uint32_t u = ((uint32_t)h) << 16;
  return __builtin_bit_cast(float, u);
}
// pack 2 f32 -> 2 bf16 in one VALU op (src0 -> low half)
__device__ inline uint32_t cvtpk_bf16(float lo, float hi) {
  uint32_t r;
  asm("v_cvt_pk_bf16_f32 %0, %1, %2" : "=v"(r) : "v"(lo), "v"(hi));
  return r;
}

// scale(1/sqrt(32)) * log2(e): folded into Q so softmax is pure exp2
#define QSCALE 0.25503486611627154f

// ---------------------------------------------------------------------------
// 0) prep: f32->bf16 weight/x pool  |  window stat (transposed)  |  bias cat
// ---------------------------------------------------------------------------
__global__ __launch_bounds__(256) void prep_kernel(
    const float* s0, const float* s1, const float* s2, const float* s3,
    const float* s4, const float* s5, const float* s6, const float* s7,
    const float* s8, const float* s9, const float* s10, const float* s11,
    unsigned short* dst,
    const float* __restrict__ gf, unsigned short* __restrict__ statT,
    const float* __restrict__ sbq, const float* __restrict__ sbk,
    const float* __restrict__ sbv, const float* __restrict__ cbk,
    const float* __restrict__ cbv, float* __restrict__ biasf) {
  const int bid = blockIdx.x;
  const int t = threadIdx.x;
  if (bid < 3200) {
    const size_t cum[13] = {0, 262144, 524288, 786432, 1048576, 1310720,
                            1572864, 1835008, 2097152, 2359296, 3407872,
                            4456448, 6553600};
    const float* srcs[12] = {s0, s1, s2, s3, s4, s5, s6, s7, s8, s9, s10, s11};
    size_t e0 = ((size_t)bid * 256 + t) * 8;
    int seg = 0;
    while (e0 >= cum[seg + 1]) ++seg;
    const float* sp = srcs[seg] + (e0 - cum[seg]);
    float4 a = *(const float4*)sp;
    float4 b = *(const float4*)(sp + 4);
    unsigned short o[8] = {f2bf(a.x), f2bf(a.y), f2bf(a.z), f2bf(a.w),
                           f2bf(b.x), f2bf(b.y), f2bf(b.z), f2bf(b.w)};
    *(uint4*)&dst[e0] = *(const uint4*)o;
  } else if (bid < 7296) {
    int gidx = (bid - 3200) * 256 + t;
    int n = gidx & 511;             // fastest: consecutive lanes -> coalesced
    int c = (gidx >> 9) & 511;
    int b = gidx >> 18;
    const float4* p = (const float4*)(gf + ((size_t)(b * 512 + c) << 13) + n * 16);
    float4 w0 = p[0], w1 = p[1], w2 = p[2], w3 = p[3];
    float mx = w0.x, mn = w0.x;
    float vals[15] = {w0.y, w0.z, w0.w, w1.x, w1.y, w1.z, w1.w,
                      w2.x, w2.y, w2.z, w2.w, w3.x, w3.y, w3.z, w3.w};
#pragma unroll
    for (int i = 0; i < 15; ++i) {
      mx = fmaxf(mx, vals[i]);
      mn = fminf(mn, vals[i]);
    }
    statT[((size_t)(b * 512 + n) << 9) + c] = f2bf(mx - mn);
  } else {
    for (int i = t; i < 2560; i += 256) {
      float v;
      if (i < 512) v = sbq[i];
      else if (i < 1024) v = sbk[i - 512];
      else if (i < 1536) v = sbv[i - 1024];
      else if (i < 2048) v = cbk[i - 1536];
      else v = cbv[i - 2048];
      biasf[i] = v;
    }
  }
}

// ---------------------------------------------------------------------------
// 2a) 128x128 / 4-wave / BK=32 GEMM body (m97 structure + 2-phase dbuf).
//     Per-wave 64x64 = 4x4 frags -> 32 FLOP/LDS-byte. Stride 64B: bank
//     groups (row parity, g) already cover 32 banks -> no swizzle needed.
// ---------------------------------------------------------------------------
__device__ __forceinline__ void gemm128_body(
    unsigned short* AsB, unsigned short* BsB,
    const unsigned short* __restrict__ A, const unsigned short* __restrict__ W,
    const float* __restrict__ bias, unsigned short* __restrict__ Cout,
    int M, int N, int K, int m0, int n0, int act, int scaleq) {
  const int t = threadIdx.x;
  const int w = t >> 6, lane = t & 63;
  const int r = lane & 15, g = lane >> 4;
  const int wm = w >> 1, wn = w & 1;

  auto STAGE = [&](int buf, int k0) {
    unsigned short* As = AsB + buf * (128 * 32);
    unsigned short* Bs = BsB + buf * (128 * 32);
#pragma unroll
    for (int ii = 0; ii < 2; ++ii) {
      int c = t + 256 * ii;            // 512 chunks/matrix: row c>>2, chunk c&3
      int row = c >> 2, sc = c & 3;
      const unsigned short* ga = A + (size_t)(m0 + row) * K + k0 + sc * 8;
      __builtin_amdgcn_global_load_lds(
          (const __attribute__((address_space(1))) uint32_t*)ga,
          (__attribute__((address_space(3))) uint32_t*)&As[c * 8], 16, 0, 0);
      const unsigned short* gb = W + (size_t)(n0 + row) * K + k0 + sc * 8;
      __builtin_amdgcn_global_load_lds(
          (const __attribute__((address_space(1))) uint32_t*)gb,
          (__attribute__((address_space(3))) uint32_t*)&Bs[c * 8], 16, 0, 0);
    }
  };

  f32x4 acc[4][4];
#pragma unroll
  for (int mi = 0; mi < 4; ++mi)
#pragma unroll
    for (int ni = 0; ni < 4; ++ni) acc[mi][ni] = (f32x4){0.f, 0.f, 0.f, 0.f};

  STAGE(0, 0);
  __syncthreads();
  int cur = 0;
  for (int k0 = 0; k0 < K; k0 += 32) {
    if (k0 + 32 < K) STAGE(cur ^ 1, k0 + 32);
    const unsigned short* As = AsB + cur * (128 * 32);
    const unsigned short* Bs = BsB + cur * (128 * 32);
    s16x8 af[4], bf[4];
#pragma unroll
    for (int mi = 0; mi < 4; ++mi)
      af[mi] = *(const s16x8*)&As[(wm * 64 + mi * 16 + r) * 32 + g * 8];
#pragma unroll
    for (int ni = 0; ni < 4; ++ni)
      bf[ni] = *(const s16x8*)&Bs[(wn * 64 + ni * 16 + r) * 32 + g * 8];
#pragma unroll
    for (int mi = 0; mi < 4; ++mi)
#pragma unroll
      for (int ni = 0; ni < 4; ++ni)
        acc[mi][ni] = __builtin_amdgcn_mfma_f32_16x16x32_bf16(
            af[mi], bf[ni], acc[mi][ni], 0, 0, 0);
    __syncthreads();
    cur ^= 1;
  }

#pragma unroll
  for (int ni = 0; ni < 4; ++ni) {
    const int col = n0 + wn * 64 + ni * 16 + r;
    const float bv = bias[col];
#pragma unroll
    for (int mi = 0; mi < 4; ++mi) {
#pragma unroll
      for (int rg = 0; rg < 4; ++rg) {
        const int row = m0 + wm * 64 + mi * 16 + g * 4 + rg;
        float v = acc[mi][ni][rg] + bv;
        if (act == 1) v = fmaxf(v, 0.f);
        if (act == 2) {
          float u = 0.7978845608028654f * (v + 0.044715f * v * v * v);
          float e = __expf(2.f * u);
          float th = 1.f - 2.f / (e + 1.f);
          v = 0.5f * v * (1.f + th);
        }
        if (scaleq && col < 512) v *= QSCALE;
        Cout[(size_t)row * N + col] = f2bf(v);
      }
    }
  }
}

// merged conv(relu) + fused-QKV dispatch: bid<64 -> conv, else qkv
__global__ __launch_bounds__(256) void gemm_conv_qkv(
    const unsigned short* __restrict__ statT,
    const unsigned short* __restrict__ convW, const float* __restrict__ convB,
    unsigned short* __restrict__ cross,
    const unsigned short* __restrict__ xbf,
    const unsigned short* __restrict__ qkvW, const float* __restrict__ qkvBias,
    unsigned short* __restrict__ qkv) {
  __shared__ __align__(16) unsigned short As[2 * 128 * 32];
  __shared__ __align__(16) unsigned short Bs[2 * 128 * 32];
  const int bid = blockIdx.x;
  if (bid < 64) {  // conv: M=2048 (16 m-tiles), N=512 (4 n-tiles)
    gemm128_body(As, Bs, statT, convW, convB, cross, 2048, 512, 512,
                 (bid >> 2) * 128, (bid & 3) * 128, 1, 0);
  } else {         // qkv: M=4096 (32 m-tiles), N=1536 (12 n-tiles)
    const int b2 = bid - 64;
    gemm128_body(As, Bs, xbf, qkvW, qkvBias, qkv, 4096, 1536, 512,
                 (b2 / 12) * 128, (b2 % 12) * 128, 0, 1);
  }
}

// plain 128x128 kernel (ffn1)
__global__ __launch_bounds__(256) void gemm128_kernel(
    const unsigned short* __restrict__ A, const unsigned short* __restrict__ W,
    const float* __restrict__ bias, unsigned short* __restrict__ C,
    int M, int N, int K, int act) {
  __shared__ __align__(16) unsigned short As[2 * 128 * 32];
  __shared__ __align__(16) unsigned short Bs[2 * 128 * 32];
  gemm128_body(As, Bs, A, W, bias, C, M, N, K,
               blockIdx.y * 128, blockIdx.x * 128, act, 0);
}

// ---------------------------------------------------------------------------
// 2b) small-N GEMM: BM=64, BN=64, BK=64, XOR swizzle, 2-phase dbuf (r6-proven)
// ---------------------------------------------------------------------------
template <int ACT, int OUTBF, int SCALEQ, int BN>
__global__ __launch_bounds__(256) void gemm_bf16(
    const unsigned short* __restrict__ A, const unsigned short* __restrict__ W,
    const float* __restrict__ bias, void* __restrict__ Cout,
    int M, int N, int K) {
  constexpr int NFR = BN / 32;
  __shared__ __align__(16) unsigned short As[2][64 * 64];
  __shared__ __align__(16) unsigned short Bs[2][BN * 64];
  const int t = threadIdx.x;
  const int w = t >> 6, lane = t & 63;
  const int r = lane & 15, g = lane >> 4;
  const int wm = w >> 1, wn = w & 1;
  const int m0 = blockIdx.y * 64, n0 = blockIdx.x * BN;

  auto STAGE = [&](int buf, int k0) {
#pragma unroll
    for (int ii = 0; ii < 2; ++ii) {
      int c = t + 256 * ii;
      int row = c >> 3, sc = c & 7;
      const unsigned short* ga =
          A + (size_t)(m0 + row) * K + k0 + ((sc ^ (row & 7)) << 3);
      __builtin_amdgcn_global_load_lds(
          (const __attribute__((address_space(1))) uint32_t*)ga,
          (__attribute__((address_space(3))) uint32_t*)&As[buf][c * 8], 16, 0, 0);
    }
#pragma unroll
    for (int ii = 0; ii < BN / 32; ++ii) {
      int c = t + 256 * ii;
      int row = c >> 3, sc = c & 7;
      const unsigned short* gb =
          W + (size_t)(n0 + row) * K + k0 + ((sc ^ (row & 7)) << 3);
      __builtin_amdgcn_global_load_lds(
          (const __attribute__((address_space(1))) uint32_t*)gb,
          (__attribute__((address_space(3))) uint32_t*)&Bs[buf][c * 8], 16, 0, 0);
    }
  };

  f32x4 acc[2][NFR];
#pragma unroll
  for (int mi = 0; mi < 2; ++mi)
#pragma unroll
    for (int ni = 0; ni < NFR; ++ni) acc[mi][ni] = (f32x4){0.f, 0.f, 0.f, 0.f};

  STAGE(0, 0);
  __syncthreads();
  int cur = 0;
  for (int k0 = 0; k0 < K; k0 += 64) {
    if (k0 + 64 < K) STAGE(cur ^ 1, k0 + 64);
#pragma unroll
    for (int ks = 0; ks < 2; ++ks) {
      s16x8 af[2], bf[NFR];
#pragma unroll
      for (int mi = 0; mi < 2; ++mi)
        af[mi] = *(const s16x8*)&As[cur][(wm * 32 + mi * 16 + r) * 64 +
                                         (((ks * 4 + g) ^ (r & 7)) << 3)];
#pragma unroll
      for (int ni = 0; ni < NFR; ++ni)
        bf[ni] = *(const s16x8*)&Bs[cur][(wn * (BN / 2) + ni * 16 + r) * 64 +
                                         (((ks * 4 + g) ^ (r & 7)) << 3)];
#pragma unroll
      for (int mi = 0; mi < 2; ++mi)
#pragma unroll
        for (int ni = 0; ni < NFR; ++ni)
          acc[mi][ni] = __builtin_amdgcn_mfma_f32_16x16x32_bf16(
              af[mi], bf[ni], acc[mi][ni], 0, 0, 0);
    }
    __syncthreads();
    cur ^= 1;
  }

#pragma unroll
  for (int ni = 0; ni < NFR; ++ni) {
    const int col = n0 + wn * (BN / 2) + ni * 16 + r;
    const float bv = bias[col];
#pragma unroll
    for (int mi = 0; mi < 2; ++mi) {
#pragma unroll
      for (int rg = 0; rg < 4; ++rg) {
        const int row = m0 + wm * 32 + mi * 16 + g * 4 + rg;
        float v = acc[mi][ni][rg] + bv;
        if (ACT == 1) v = fmaxf(v, 0.f);
        if (ACT == 2) {
          float u = 0.7978845608028654f * (v + 0.044715f * v * v * v);
          float e = __expf(2.f * u);
          float th = 1.f - 2.f / (e + 1.f);
          v = 0.5f * v * (1.f + th);
        }
        if (SCALEQ && col < 512) v *= QSCALE;
        if (OUTBF)
          ((unsigned short*)Cout)[(size_t)row * N + col] = f2bf(v);
        else
          ((float*)Cout)[(size_t)row * N + col] = v;
      }
    }
  }
}

// ---------------------------------------------------------------------------
// 4) MFMA flash attention (r6-proven): swapped operands, fused V-transpose,
//    T14 async-stage, T5 setprio. Block = (128 q, head, batch), 8 waves.
// ---------------------------------------------------------------------------
template <int S>
__global__ __launch_bounds__(512) void attn_mfma(
    const unsigned short* __restrict__ Q, int qstride,
    const unsigned short* __restrict__ K, int kstride,
    const unsigned short* __restrict__ V, int vstride,
    unsigned short* __restrict__ O) {
  constexpr int NT = S / 128;
  __shared__ __align__(16) unsigned short Kl[128 * 40];
  __shared__ __align__(16) unsigned short Vl[32 * 136];
  __shared__ __align__(16) unsigned short Pl[8][16 * 136];
  const int t = threadIdx.x;
  const int w = t >> 6, lane = t & 63;
  const int r = lane & 15, g = lane >> 4;
  const int qt = blockIdx.x, h = blockIdx.y, b = blockIdx.z;
  const int q0 = qt * 128 + w * 16;
  const int kvr = t >> 2, dsg = t & 3;

  s16x8 qa = *(const s16x8*)&Q[((size_t)(b * 1024 + q0 + r)) * qstride + h * 32 + g * 8];

  f32x4 o0 = (f32x4){0.f, 0.f, 0.f, 0.f};
  f32x4 o1 = (f32x4){0.f, 0.f, 0.f, 0.f};
  float m = -1e30f, l = 0.f;

  uint4 kA = {}, vA = {}, kB = {}, vB = {};
  auto GLOAD = [&](int nt, uint4& kr, uint4& vr) {
    const int kv0 = nt * 128;
    kr = *(const uint4*)&K[((size_t)(b * S + kv0 + kvr)) * kstride + h * 32 + dsg * 8];
    vr = *(const uint4*)&V[((size_t)(b * S + kv0 + kvr)) * vstride + h * 32 + dsg * 8];
  };
  GLOAD(0, kA, vA);

  for (int nt = 0; nt < NT; ++nt) {
    __syncthreads();
    *(uint4*)&Kl[kvr * 40 + dsg * 8] = kA;
    {
      unsigned short vs[8];
      *(uint4*)vs = vA;
#pragma unroll
      for (int u = 0; u < 8; ++u) Vl[(dsg * 8 + u) * 136 + kvr] = vs[u];
    }
    if (nt + 1 < NT) GLOAD(nt + 1, kB, vB);
    __syncthreads();

    f32x4 s[8];
    __builtin_amdgcn_s_setprio(1);
#pragma unroll
    for (int nb = 0; nb < 8; ++nb) {
      s16x8 ka = *(const s16x8*)&Kl[(nb * 16 + r) * 40 + g * 8];
      s[nb] = __builtin_amdgcn_mfma_f32_16x16x32_bf16(
          ka, qa, (f32x4){0.f, 0.f, 0.f, 0.f}, 0, 0, 0);
    }
    __builtin_amdgcn_s_setprio(0);

    float tm = -1e30f;
#pragma unroll
    for (int nb = 0; nb < 8; ++nb) {
      float a01 = fmaxf(s[nb][0], s[nb][1]);
      float a23 = fmaxf(s[nb][2], s[nb][3]);
      tm = fmaxf(tm, fmaxf(a01, a23));
    }
    tm = fmaxf(tm, __shfl_xor(tm, 16));
    tm = fmaxf(tm, __shfl_xor(tm, 32));
    const float mnew = fmaxf(m, tm);
    const float corr = __builtin_amdgcn_exp2f(m - mnew);
    float ps = 0.f;
#pragma unroll
    for (int nb = 0; nb < 8; ++nb) {
      float p0 = __builtin_amdgcn_exp2f(s[nb][0] - mnew);
      float p1 = __builtin_amdgcn_exp2f(s[nb][1] - mnew);
      float p2 = __builtin_amdgcn_exp2f(s[nb][2] - mnew);
      float p3 = __builtin_amdgcn_exp2f(s[nb][3] - mnew);
      ps += (p0 + p1) + (p2 + p3);
      uint2 pv;
      pv.x = cvtpk_bf16(p0, p1);
      pv.y = cvtpk_bf16(p2, p3);
      *(uint2*)&Pl[w][r * 136 + nb * 16 + g * 4] = pv;
    }
    ps += __shfl_xor(ps, 16);
    ps += __shfl_xor(ps, 32);
    l = l * corr + ps;
    m = mnew;
#pragma unroll
    for (int rg = 0; rg < 4; ++rg) { o0[rg] *= corr; o1[rg] *= corr; }

    __builtin_amdgcn_s_setprio(1);
#pragma unroll
    for (int ks = 0; ks < 4; ++ks) {
      s16x8 va0 = *(const s16x8*)&Vl[r * 136 + ks * 32 + g * 8];
      s16x8 va1 = *(const s16x8*)&Vl[(16 + r) * 136 + ks * 32 + g * 8];
      s16x8 pb  = *(const s16x8*)&Pl[w][r * 136 + ks * 32 + g * 8];
      o0 = __builtin_amdgcn_mfma_f32_16x16x32_bf16(va0, pb, o0, 0, 0, 0);
      o1 = __builtin_amdgcn_mfma_f32_16x16x32_bf16(va1, pb, o1, 0, 0, 0);
    }
    __builtin_amdgcn_s_setprio(0);
    kA = kB; vA = vB;
  }

  const float inv = 1.f / l;
  const size_t row = (size_t)(b * 1024 + q0 + r);
  uint2 w0, w1;
  w0.x = cvtpk_bf16(o0[0] * inv, o0[1] * inv);
  w0.y = cvtpk_bf16(o0[2] * inv, o0[3] * inv);
  w1.x = cvtpk_bf16(o1[0] * inv, o1[1] * inv);
  w1.y = cvtpk_bf16(o1[2] * inv, o1[3] * inv);
  *(uint2*)&O[row * 512 + h * 32 + g * 4]      = w0;
  *(uint2*)&O[row * 512 + h * 32 + 16 + g * 4] = w1;
}

// ---------------------------------------------------------------------------
// 5) LayerNorm(X + A) * g + b -> bf16 [row][512]
// ---------------------------------------------------------------------------
template <int XBF, int ABF>
__global__ __launch_bounds__(256) void ln_kernel(
    const void* __restrict__ X, const void* __restrict__ A,
    const float* __restrict__ gw, const float* __restrict__ bw,
    unsigned short* __restrict__ O) {
  const int rr = blockIdx.x;
  const int t = threadIdx.x;
  const size_t base = (size_t)rr * 512;
  float x0, x1, a0, a1;
  if (XBF) {
    x0 = bf2f(((const unsigned short*)X)[base + t]);
    x1 = bf2f(((const unsigned short*)X)[base + t + 256]);
  } else {
    x0 = ((const float*)X)[base + t];
    x1 = ((const float*)X)[base + t + 256];
  }
  if (ABF) {
    a0 = bf2f(((const unsigned short*)A)[base + t]);
    a1 = bf2f(((const unsigned short*)A)[base + t + 256]);
  } else {
    a0 = ((const float*)A)[base + t];
    a1 = ((const float*)A)[base + t + 256];
  }
  float v0 = x0 + a0;
  float v1 = x1 + a1;
  __shared__ float wsum[4];
  float s = v0 + v1;
#pragma unroll
  for (int of = 32; of; of >>= 1) s += __shfl_down(s, of);
  if ((t & 63) == 0) wsum[t >> 6] = s;
  __syncthreads();
  const float mean = (wsum[0] + wsum[1] + wsum[2] + wsum[3]) * (1.f / 512.f);
  __syncthreads();
  float d0 = v0 - mean, d1 = v1 - mean;
  float s2 = d0 * d0 + d1 * d1;
#pragma unroll
  for (int of = 32; of; of >>= 1) s2 += __shfl_down(s2, of);
  if ((t & 63) == 0) wsum[t >> 6] = s2;
  __syncthreads();
  const float var = (wsum[0] + wsum[1] + wsum[2] + wsum[3]) * (1.f / 512.f);
  const float rstd = rsqrtf(var + 1e-5f);
  O[base + t] = f2bf(d0 * rstd * gw[t] + bw[t]);
  O[base + t + 256] = f2bf(d1 * rstd * gw[t + 256] + bw[t + 256]);
}

// ---------------------------------------------------------------------------
// 6) final transpose: h3 bf16 [b*1024+l][512] -> out f32 [b][c][l]
// ---------------------------------------------------------------------------
__global__ __launch_bounds__(256) void transpose_out_kernel(
    const unsigned short* __restrict__ h3, float* __restrict__ out) {
  __shared__ float tile[64][65];
  const int t = threadIdx.x;
  const int lt = blockIdx.x * 64, ct = blockIdx.y * 64, b = blockIdx.z;
#pragma unroll
  for (int ii = 0; ii < 2; ++ii) {
    int idx = t + 256 * ii;
    int row = idx >> 3, ch = idx & 7;
    uint4 v = *(const uint4*)&h3[((size_t)(b * 1024 + lt + row)) * 512 + ct + ch * 8];
    unsigned short vs[8];
    *(uint4*)vs = v;
#pragma unroll
    for (int u = 0; u < 8; ++u) tile[row][ch * 8 + u] = bf2f(vs[u]);
  }
  __syncthreads();
  const int c = t >> 2, l0 = (t & 3) * 16;
  float* op = &out[((size_t)(b * 512 + ct + c)) * 1024 + lt + l0];
#pragma unroll
  for (int i = 0; i < 4; ++i) {
    float4 o4 = {tile[l0 + i * 4 + 0][c], tile[l0 + i * 4 + 1][c],
                 tile[l0 + i * 4 + 2][c], tile[l0 + i * 4 + 3][c]};
    *(float4*)(op + i * 4) = o4;
  }
}

// ---------------------------------------------------------------------------
extern "C" void kernel_launch(void* const* d_in, const int* in_sizes, int n_in,
                              void* d_out, int out_size, void* d_ws, size_t ws_size,
                              hipStream_t stream) {
  const float* x      = (const float*)d_in[0];
  const float* gf     = (const float*)d_in[1];
  const float* conv_w = (const float*)d_in[2];
  const float* conv_b = (const float*)d_in[3];
  const float* sWq = (const float*)d_in[4],  *sbq = (const float*)d_in[5];
  const float* sWk = (const float*)d_in[6],  *sbk = (const float*)d_in[7];
  const float* sWv = (const float*)d_in[8],  *sbv = (const float*)d_in[9];
  const float* sWo = (const float*)d_in[10], *sbo = (const float*)d_in[11];
  const float* cWq = (const float*)d_in[12], *cbq = (const float*)d_in[13];
  const float* cWk = (const float*)d_in[14], *cbk = (const float*)d_in[15];
  const float* cWv = (const float*)d_in[16], *cbv = (const float*)d_in[17];
  const float* cWo = (const float*)d_in[18], *cbo = (const float*)d_in[19];
  const float* fw1 = (const float*)d_in[20], *fb1 = (const float*)d_in[21];
  const float* fw2 = (const float*)d_in[22], *fb2 = (const float*)d_in[23];
  const float* ln1_g = (const float*)d_in[24], *ln1_b = (const float*)d_in[25];
  const float* ln2_g = (const float*)d_in[26], *ln2_b = (const float*)d_in[27];
  const float* ln3_g = (const float*)d_in[28], *ln3_b = (const float*)d_in[29];
  float* out = (float*)d_out;

  // bf16 conversion pool (ushort element offsets):
  unsigned short* bfp = (unsigned short*)d_ws;
  unsigned short* conv_wb = bfp + 0;
  unsigned short* sWqb = bfp + 262144;   // [Wq;Wk;Wv] contiguous = fused QKV W
  unsigned short* cWqb = bfp + 1310720;
  unsigned short* cWkb = bfp + 1572864;  // [cWk;cWv] contiguous = fused cKV W
  unsigned short* cWob = bfp + 2097152;
  unsigned short* sWob = bfp + 1048576;
  unsigned short* fw1b = bfp + 2359296, *fw2b = bfp + 3407872;
  unsigned short* xbf  = bfp + 4456448;  // pool ends at el 6,553,600

  unsigned short* SC   = bfp + 6553600;
  unsigned short* qkvb = SC;                  // 6,291,456  [4096][1536]
  unsigned short* ckvb = SC + 6291456;        // 2,097,152  [2048][1024]
  unsigned short* qcb  = SC + 8388608;        // 2,097,152  (statTb overlays)
  unsigned short* ctxb = SC + 12582912;       // 2,097,152  (crossb overlays)
  unsigned short* projb= SC + 14680064;       // 2,097,152  (biasf overlays head)
  unsigned short* hbf  = SC + 16777216;       // 2,097,152  (h3 reuses)
  unsigned short* h2bf = SC + 18874368;       // 2,097,152
  unsigned short* statTb = qcb;
  unsigned short* crossb = ctxb;
  unsigned short* midb   = qkvb;              // 8,388,608 (qkvb+ckvb dead then)
  float* biasf = (float*)projb;               // [1536 qkv | 1024 ckv] f32

  prep_kernel<<<7297, 256, 0, stream>>>(
      conv_w, sWq, sWk, sWv, sWo, cWq, cWk, cWv, cWo, fw1, fw2, x, bfp,
      gf, statTb, sbq, sbk, sbv, cbk, cbv, biasf);

  // merged: conv(relu, 64 blocks) + fused self-QKV (384 blocks), 128x128 tiles
  gemm_conv_qkv<<<448, 256, 0, stream>>>(
      statTb, conv_wb, conv_b, crossb, xbf, sWqb, biasf, qkvb);

  // fused cross KV [2048][1024]
  gemm_bf16<0, 1, 0, 64><<<dim3(16, 32), 256, 0, stream>>>(
      crossb, cWkb, biasf + 1536, ckvb, 2048, 1024, 512);

  // self-attention (V transpose fused in staging)
  attn_mfma<1024><<<dim3(8, 16, 4), 512, 0, stream>>>(
      qkvb, 1536, qkvb + 512, 1536, qkvb + 1024, 1536, ctxb);
  gemm_bf16<0, 1, 0, 64><<<dim3(8, 64), 256, 0, stream>>>(
      ctxb, sWob, sbo, projb, 4096, 512, 512);
  ln_kernel<0, 1><<<4096, 256, 0, stream>>>(x, projb, ln1_g, ln1_b, hbf);

  // cross-attention (K/V from conv tokens, S=512)
  gemm_bf16<0, 1, 1, 64><<<dim3(8, 64), 256, 0, stream>>>(
      hbf, cWqb, cbq, qcb, 4096, 512, 512);
  attn_mfma<512><<<dim3(8, 16, 4), 512, 0, stream>>>(
      qcb, 512, ckvb, 1024, ckvb + 512, 1024, ctxb);
  gemm_bf16<0, 1, 0, 64><<<dim3(8, 64), 256, 0, stream>>>(
      ctxb, cWob, cbo, projb, 4096, 512, 512);
  ln_kernel<1, 1><<<4096, 256, 0, stream>>>(hbf, projb, ln2_g, ln2_b, h2bf);

  // FFN (ffn1 as 128x128, gelu) + final LN + transpose
  gemm128_kernel<<<dim3(16, 32), 256, 0, stream>>>(
      h2bf, fw1b, fb1, midb, 4096, 2048, 512, 2);
  gemm_bf16<0, 1, 0, 64><<<dim3(8, 64), 256, 0, stream>>>(
      midb, fw2b, fb2, projb, 4096, 512, 2048);
  ln_kernel<1, 1><<<4096, 256, 0, stream>>>(h2bf, projb, ln3_g, ln3_b, hbf);
  transpose_out_kernel<<<dim3(16, 8, 4), 256, 0, stream>>>(hbf, out);
}